// Round 1
// baseline (1823.157 us; speedup 1.0000x reference)
//
#include <hip/hip_runtime.h>
#include <hip/hip_bf16.h>
#include <math.h>
#include <stdint.h>

#define HEADS 4
#define CH 64          // channels per head
#define HC 256         // HEADS*CH
#define NEG 0.2f
#define EPSV 1e-16f

__device__ __forceinline__ float lrelu(float x) { return x > 0.f ? x : NEG * x; }

// float atomic max via sign-split int/uint atomics (works for mixed signs,
// init must be a real float value)
__device__ __forceinline__ void atomicMaxF32(float* addr, float val) {
  if (val >= 0.f) atomicMax((int*)addr, __float_as_int(val));
  else            atomicMin((unsigned int*)addr, __float_as_uint(val));
}

// ---------------- GEMM: C[M,256] = A[M,K] x B[K,256], f32 ----------------
__global__ __launch_bounds__(256) void gemm_k(const float* __restrict__ A,
                                              const float* __restrict__ B,
                                              float* __restrict__ C,
                                              int M, int K) {
  const int BM = 64, BN = 64, BK = 16;
  __shared__ float As[BK][BM + 4];   // row base 68 floats = 272B, 16B-aligned
  __shared__ float Bs[BK][BN];
  int bm = blockIdx.x * BM, bn = blockIdx.y * BN;
  int tid = threadIdx.x;
  int tx = tid & 15, ty = tid >> 4;
  float acc[4][4] = {};
  for (int k0 = 0; k0 < K; k0 += BK) {
    // stage A: 64 rows x 16 k, one float4 per thread (transposed into LDS)
    {
      int r  = tid >> 2;
      int kq = (tid & 3) << 2;
      int gr = bm + r;
      float4 v = make_float4(0.f, 0.f, 0.f, 0.f);
      if (gr < M) v = *reinterpret_cast<const float4*>(A + (size_t)gr * K + k0 + kq);
      As[kq + 0][r] = v.x; As[kq + 1][r] = v.y; As[kq + 2][r] = v.z; As[kq + 3][r] = v.w;
    }
    // stage B: 16 k-rows x 64 cols, coalesced
    {
      int kk = tid >> 6;     // 0..3
      int c  = tid & 63;
      #pragma unroll
      for (int q = 0; q < 4; ++q)
        Bs[kk * 4 + q][c] = B[(size_t)(k0 + kk * 4 + q) * HC + bn + c];
    }
    __syncthreads();
    #pragma unroll
    for (int kk = 0; kk < BK; ++kk) {
      float4 av = *reinterpret_cast<const float4*>(&As[kk][ty * 4]);
      float4 bv = *reinterpret_cast<const float4*>(&Bs[kk][tx * 4]);
      float ar[4] = {av.x, av.y, av.z, av.w};
      float br[4] = {bv.x, bv.y, bv.z, bv.w};
      #pragma unroll
      for (int i = 0; i < 4; ++i)
        #pragma unroll
        for (int j = 0; j < 4; ++j)
          acc[i][j] += ar[i] * br[j];
    }
    __syncthreads();
  }
  #pragma unroll
  for (int i = 0; i < 4; ++i) {
    int gr = bm + ty * 4 + i;
    if (gr < M) {
      float4 o = make_float4(acc[i][0], acc[i][1], acc[i][2], acc[i][3]);
      *reinterpret_cast<float4*>(C + (size_t)gr * HC + bn + tx * 4) = o;
    }
  }
}

// ------------- per-node: a_src/a_dst dots, m init (self-loop), acc zero -------------
__global__ __launch_bounds__(256) void node_att_k(const float* __restrict__ hbuf,
                                                  const float* __restrict__ att_s,
                                                  const float* __restrict__ att_d,
                                                  float* __restrict__ a_src,
                                                  float* __restrict__ a_dst,
                                                  float* __restrict__ mmax,
                                                  float* __restrict__ acc,
                                                  int N) {
  int wid  = (blockIdx.x * blockDim.x + threadIdx.x) >> 6;
  int lane = threadIdx.x & 63;
  if (wid >= N) return;
  const float* hr = hbuf + (size_t)wid * HC;
  float as_h[HEADS], ad_h[HEADS];
  #pragma unroll
  for (int hh = 0; hh < HEADS; ++hh) {
    float hv = hr[hh * CH + lane];
    float ps = hv * att_s[hh * CH + lane];
    float pd = hv * att_d[hh * CH + lane];
    #pragma unroll
    for (int off = 32; off > 0; off >>= 1) {
      ps += __shfl_xor(ps, off);
      pd += __shfl_xor(pd, off);
    }
    as_h[hh] = ps; ad_h[hh] = pd;
  }
  if (lane == 0) {
    #pragma unroll
    for (int hh = 0; hh < HEADS; ++hh) {
      a_src[(size_t)wid * 4 + hh] = as_h[hh];
      a_dst[(size_t)wid * 4 + hh] = ad_h[hh];
      mmax[(size_t)wid * 4 + hh]  = lrelu(as_h[hh] + ad_h[hh]);  // self-loop seed
    }
  }
  acc[(size_t)wid * CH + lane] = 0.f;
}

// ------------- edge pass 1: segment max -------------
__global__ __launch_bounds__(256) void edge_max_k(const int* __restrict__ src,
                                                  const int* __restrict__ dst,
                                                  const float* __restrict__ a_src,
                                                  const float* __restrict__ a_dst,
                                                  float* __restrict__ mmax,
                                                  int E) {
  int e = blockIdx.x * blockDim.x + threadIdx.x;
  if (e >= E) return;
  int s = src[e], d = dst[e];
  float4 as4 = *reinterpret_cast<const float4*>(a_src + (size_t)s * 4);
  float4 ad4 = *reinterpret_cast<const float4*>(a_dst + (size_t)d * 4);
  atomicMaxF32(&mmax[(size_t)d * 4 + 0], lrelu(as4.x + ad4.x));
  atomicMaxF32(&mmax[(size_t)d * 4 + 1], lrelu(as4.y + ad4.y));
  atomicMaxF32(&mmax[(size_t)d * 4 + 2], lrelu(as4.z + ad4.z));
  atomicMaxF32(&mmax[(size_t)d * 4 + 3], lrelu(as4.w + ad4.w));
}

// ------------- per (node,head): denom = exp(e_self - m) -------------
__global__ __launch_bounds__(256) void node_denom_k(const float* __restrict__ a_src,
                                                    const float* __restrict__ a_dst,
                                                    const float* __restrict__ mmax,
                                                    float* __restrict__ denom,
                                                    int total) {
  int i = blockIdx.x * blockDim.x + threadIdx.x;
  if (i >= total) return;
  float e_self = lrelu(a_src[i] + a_dst[i]);
  denom[i] = expf(e_self - mmax[i]);
}

// ------------- edge pass 2: segment sum of exp -------------
__global__ __launch_bounds__(256) void edge_sum_k(const int* __restrict__ src,
                                                  const int* __restrict__ dst,
                                                  const float* __restrict__ a_src,
                                                  const float* __restrict__ a_dst,
                                                  const float* __restrict__ mmax,
                                                  float* __restrict__ denom,
                                                  int E) {
  int e = blockIdx.x * blockDim.x + threadIdx.x;
  if (e >= E) return;
  int s = src[e], d = dst[e];
  float4 as4 = *reinterpret_cast<const float4*>(a_src + (size_t)s * 4);
  float4 ad4 = *reinterpret_cast<const float4*>(a_dst + (size_t)d * 4);
  float4 m4  = *reinterpret_cast<const float4*>(mmax  + (size_t)d * 4);
  atomicAdd(&denom[(size_t)d * 4 + 0], expf(lrelu(as4.x + ad4.x) - m4.x));
  atomicAdd(&denom[(size_t)d * 4 + 1], expf(lrelu(as4.y + ad4.y) - m4.y));
  atomicAdd(&denom[(size_t)d * 4 + 2], expf(lrelu(as4.z + ad4.z) - m4.z));
  atomicAdd(&denom[(size_t)d * 4 + 3], expf(lrelu(as4.w + ad4.w) - m4.w));
}

// ------------- edge pass 3: message aggregation (wave per edge) -------------
__global__ __launch_bounds__(256) void edge_agg_k(const int* __restrict__ src,
                                                  const int* __restrict__ dst,
                                                  const float* __restrict__ a_src,
                                                  const float* __restrict__ a_dst,
                                                  const float* __restrict__ mmax,
                                                  const float* __restrict__ denom,
                                                  const float* __restrict__ hbuf,
                                                  float* __restrict__ acc,
                                                  int E) {
  int wid  = (blockIdx.x * blockDim.x + threadIdx.x) >> 6;
  int lane = threadIdx.x & 63;
  if (wid >= E) return;
  int s = src[wid], d = dst[wid];
  float4 as4 = *reinterpret_cast<const float4*>(a_src + (size_t)s * 4);
  float4 ad4 = *reinterpret_cast<const float4*>(a_dst + (size_t)d * 4);
  float4 m4  = *reinterpret_cast<const float4*>(mmax  + (size_t)d * 4);
  float4 dn4 = *reinterpret_cast<const float4*>(denom + (size_t)d * 4);
  float al0 = expf(lrelu(as4.x + ad4.x) - m4.x) / (dn4.x + EPSV);
  float al1 = expf(lrelu(as4.y + ad4.y) - m4.y) / (dn4.y + EPSV);
  float al2 = expf(lrelu(as4.z + ad4.z) - m4.z) / (dn4.z + EPSV);
  float al3 = expf(lrelu(as4.w + ad4.w) - m4.w) / (dn4.w + EPSV);
  const float* hr = hbuf + (size_t)s * HC;
  float sum = al0 * hr[lane] + al1 * hr[CH + lane] + al2 * hr[2 * CH + lane] + al3 * hr[3 * CH + lane];
  atomicAdd(&acc[(size_t)d * CH + lane], sum);
}

// ------------- finalize: self msg + mean heads + bias + relu (+log_softmax) -------------
__global__ __launch_bounds__(256) void finalize_k(const float* __restrict__ a_src,
                                                  const float* __restrict__ a_dst,
                                                  const float* __restrict__ mmax,
                                                  const float* __restrict__ denom,
                                                  const float* __restrict__ hbuf,
                                                  const float* __restrict__ acc,
                                                  const float* __restrict__ bias,
                                                  float* __restrict__ outp,
                                                  int N, int do_lsm) {
  int wid  = (blockIdx.x * blockDim.x + threadIdx.x) >> 6;
  int lane = threadIdx.x & 63;
  if (wid >= N) return;
  float4 as4 = *reinterpret_cast<const float4*>(a_src + (size_t)wid * 4);
  float4 ad4 = *reinterpret_cast<const float4*>(a_dst + (size_t)wid * 4);
  float4 m4  = *reinterpret_cast<const float4*>(mmax  + (size_t)wid * 4);
  float4 dn4 = *reinterpret_cast<const float4*>(denom + (size_t)wid * 4);
  float al0 = expf(lrelu(as4.x + ad4.x) - m4.x) / (dn4.x + EPSV);
  float al1 = expf(lrelu(as4.y + ad4.y) - m4.y) / (dn4.y + EPSV);
  float al2 = expf(lrelu(as4.z + ad4.z) - m4.z) / (dn4.z + EPSV);
  float al3 = expf(lrelu(as4.w + ad4.w) - m4.w) / (dn4.w + EPSV);
  const float* hr = hbuf + (size_t)wid * HC;
  float sum = acc[(size_t)wid * CH + lane]
            + al0 * hr[lane] + al1 * hr[CH + lane]
            + al2 * hr[2 * CH + lane] + al3 * hr[3 * CH + lane];
  float v = sum * 0.25f + bias[lane];
  v = fmaxf(v, 0.f);
  if (do_lsm) {
    float mx = v;
    #pragma unroll
    for (int off = 32; off > 0; off >>= 1) mx = fmaxf(mx, __shfl_xor(mx, off));
    float ex = expf(v - mx);
    float sm = ex;
    #pragma unroll
    for (int off = 32; off > 0; off >>= 1) sm += __shfl_xor(sm, off);
    outp[(size_t)wid * CH + lane] = v - mx - logf(sm);
  } else {
    outp[(size_t)wid * CH + lane] = v;
  }
}

extern "C" void kernel_launch(void* const* d_in, const int* in_sizes, int n_in,
                              void* d_out, int out_size, void* d_ws, size_t ws_size,
                              hipStream_t stream) {
  const float* x0 = (const float*)d_in[0];
  const int*   ei = (const int*)d_in[1];
  int N = in_sizes[0] / HC;   // 50000 (C_IN==256==HC)
  int E = in_sizes[1] / 2;    // 800000
  const int* srcp = ei;
  const int* dstp = ei + E;

  const float* W[3]  = {(const float*)d_in[2], (const float*)d_in[6],  (const float*)d_in[10]};
  const float* AS[3] = {(const float*)d_in[3], (const float*)d_in[7],  (const float*)d_in[11]};
  const float* AD[3] = {(const float*)d_in[4], (const float*)d_in[8],  (const float*)d_in[12]};
  const float* BI[3] = {(const float*)d_in[5], (const float*)d_in[9],  (const float*)d_in[13]};
  int Kdim[3] = {256, 64, 64};

  char* ws = (char*)d_ws;
  size_t off = 0;
  auto alloc = [&](size_t bytes) {
    void* p = ws + off;
    off += (bytes + 255) & ~(size_t)255;
    return p;
  };
  float* hbuf = (float*)alloc((size_t)N * HC * 4);   // 51.2 MB
  float* acc  = (float*)alloc((size_t)N * CH * 4);   // 12.8 MB
  float* xbuf = (float*)alloc((size_t)N * CH * 4);   // 12.8 MB
  float* a_s  = (float*)alloc((size_t)N * 4 * 4);
  float* a_d  = (float*)alloc((size_t)N * 4 * 4);
  float* mm   = (float*)alloc((size_t)N * 4 * 4);
  float* dn   = (float*)alloc((size_t)N * 4 * 4);

  const float* xin = x0;
  for (int L = 0; L < 3; ++L) {
    int K = Kdim[L];
    dim3 ggrid((N + 63) / 64, 4);
    gemm_k<<<ggrid, 256, 0, stream>>>(xin, W[L], hbuf, N, K);
    node_att_k<<<(N + 3) / 4, 256, 0, stream>>>(hbuf, AS[L], AD[L], a_s, a_d, mm, acc, N);
    edge_max_k<<<(E + 255) / 256, 256, 0, stream>>>(srcp, dstp, a_s, a_d, mm, E);
    node_denom_k<<<(N * 4 + 255) / 256, 256, 0, stream>>>(a_s, a_d, mm, dn, N * 4);
    edge_sum_k<<<(E + 255) / 256, 256, 0, stream>>>(srcp, dstp, a_s, a_d, mm, dn, E);
    edge_agg_k<<<(E + 3) / 4, 256, 0, stream>>>(srcp, dstp, a_s, a_d, mm, dn, hbuf, acc, E);
    float* outp = (L == 2) ? (float*)d_out : xbuf;
    finalize_k<<<(N + 3) / 4, 256, 0, stream>>>(a_s, a_d, mm, dn, hbuf, acc, BI[L], outp, N, (L == 2) ? 1 : 0);
    xin = xbuf;
  }
}

// Round 2
// 1717.656 us; speedup vs baseline: 1.0614x; 1.0614x over previous
//
#include <hip/hip_runtime.h>
#include <hip/hip_bf16.h>
#include <math.h>
#include <stdint.h>

#define HEADS 4
#define CH 64          // channels per head
#define HC 256         // HEADS*CH
#define NEG 0.2f
#define EPSV 1e-16f

__device__ __forceinline__ float lrelu(float x) { return x > 0.f ? x : NEG * x; }

__device__ __forceinline__ unsigned short f2bf(float f) {
  __hip_bfloat16 b = __float2bfloat16(f);   // RNE
  return *reinterpret_cast<unsigned short*>(&b);
}
__device__ __forceinline__ float bf2f(unsigned short u) {
  return __uint_as_float((unsigned)u << 16);
}

// float atomic max via sign-split int/uint atomics
__device__ __forceinline__ void atomicMaxF32(float* addr, float val) {
  if (val >= 0.f) atomicMax((int*)addr, __float_as_int(val));
  else            atomicMin((unsigned int*)addr, __float_as_uint(val));
}

// ---------------- GEMM: C[M,256] = A[M,K] x B[K,256], f32 ----------------
__global__ __launch_bounds__(256) void gemm_k(const float* __restrict__ A,
                                              const float* __restrict__ B,
                                              float* __restrict__ C,
                                              int M, int K) {
  const int BM = 64, BN = 64, BK = 16;
  __shared__ float As[BK][BM + 4];
  __shared__ float Bs[BK][BN];
  int bm = blockIdx.x * BM, bn = blockIdx.y * BN;
  int tid = threadIdx.x;
  int tx = tid & 15, ty = tid >> 4;
  float acc[4][4] = {};
  for (int k0 = 0; k0 < K; k0 += BK) {
    {
      int r  = tid >> 2;
      int kq = (tid & 3) << 2;
      int gr = bm + r;
      float4 v = make_float4(0.f, 0.f, 0.f, 0.f);
      if (gr < M) v = *reinterpret_cast<const float4*>(A + (size_t)gr * K + k0 + kq);
      As[kq + 0][r] = v.x; As[kq + 1][r] = v.y; As[kq + 2][r] = v.z; As[kq + 3][r] = v.w;
    }
    {
      int kk = tid >> 6;
      int c  = tid & 63;
      #pragma unroll
      for (int q = 0; q < 4; ++q)
        Bs[kk * 4 + q][c] = B[(size_t)(k0 + kk * 4 + q) * HC + bn + c];
    }
    __syncthreads();
    #pragma unroll
    for (int kk = 0; kk < BK; ++kk) {
      float4 av = *reinterpret_cast<const float4*>(&As[kk][ty * 4]);
      float4 bv = *reinterpret_cast<const float4*>(&Bs[kk][tx * 4]);
      float ar[4] = {av.x, av.y, av.z, av.w};
      float br[4] = {bv.x, bv.y, bv.z, bv.w};
      #pragma unroll
      for (int i = 0; i < 4; ++i)
        #pragma unroll
        for (int j = 0; j < 4; ++j)
          acc[i][j] += ar[i] * br[j];
    }
    __syncthreads();
  }
  #pragma unroll
  for (int i = 0; i < 4; ++i) {
    int gr = bm + ty * 4 + i;
    if (gr < M) {
      float4 o = make_float4(acc[i][0], acc[i][1], acc[i][2], acc[i][3]);
      *reinterpret_cast<float4*>(C + (size_t)gr * HC + bn + tx * 4) = o;
    }
  }
}

// ------------- per-node: a_src/a_dst dots, m init (self-loop), acc zero,
//               bf16 channel-major copy of h -------------
__global__ __launch_bounds__(256) void node_att_k(const float* __restrict__ hbuf,
                                                  const float* __restrict__ att_s,
                                                  const float* __restrict__ att_d,
                                                  float* __restrict__ a_src,
                                                  float* __restrict__ a_dst,
                                                  float* __restrict__ mmax,
                                                  float* __restrict__ acc,
                                                  unsigned short* __restrict__ hb16,
                                                  int N) {
  int wid  = (blockIdx.x * blockDim.x + threadIdx.x) >> 6;
  int lane = threadIdx.x & 63;
  if (wid >= N) return;
  const float* hr = hbuf + (size_t)wid * HC;
  float as_h[HEADS], ad_h[HEADS];
  ushort4 pack;
  unsigned short* pk = reinterpret_cast<unsigned short*>(&pack);
  #pragma unroll
  for (int hh = 0; hh < HEADS; ++hh) {
    float hv = hr[hh * CH + lane];
    pk[hh] = f2bf(hv);
    float ps = hv * att_s[hh * CH + lane];
    float pd = hv * att_d[hh * CH + lane];
    #pragma unroll
    for (int off = 32; off > 0; off >>= 1) {
      ps += __shfl_xor(ps, off);
      pd += __shfl_xor(pd, off);
    }
    as_h[hh] = ps; ad_h[hh] = pd;
  }
  // channel-major: hb16[node][chan][head]
  *reinterpret_cast<ushort4*>(hb16 + (size_t)wid * HC + lane * 4) = pack;
  if (lane == 0) {
    #pragma unroll
    for (int hh = 0; hh < HEADS; ++hh) {
      a_src[(size_t)wid * 4 + hh] = as_h[hh];
      a_dst[(size_t)wid * 4 + hh] = ad_h[hh];
      mmax[(size_t)wid * 4 + hh]  = lrelu(as_h[hh] + ad_h[hh]);  // self-loop seed
    }
  }
  acc[(size_t)wid * CH + lane] = 0.f;
}

// ------------- edge pass 1: segment max -------------
__global__ __launch_bounds__(256) void edge_max_k(const int* __restrict__ src,
                                                  const int* __restrict__ dst,
                                                  const float* __restrict__ a_src,
                                                  const float* __restrict__ a_dst,
                                                  float* __restrict__ mmax,
                                                  int E) {
  int e = blockIdx.x * blockDim.x + threadIdx.x;
  if (e >= E) return;
  int s = src[e], d = dst[e];
  float4 as4 = *reinterpret_cast<const float4*>(a_src + (size_t)s * 4);
  float4 ad4 = *reinterpret_cast<const float4*>(a_dst + (size_t)d * 4);
  atomicMaxF32(&mmax[(size_t)d * 4 + 0], lrelu(as4.x + ad4.x));
  atomicMaxF32(&mmax[(size_t)d * 4 + 1], lrelu(as4.y + ad4.y));
  atomicMaxF32(&mmax[(size_t)d * 4 + 2], lrelu(as4.z + ad4.z));
  atomicMaxF32(&mmax[(size_t)d * 4 + 3], lrelu(as4.w + ad4.w));
}

// ------------- per (node,head): denom seed = exp(e_self - m) -------------
__global__ __launch_bounds__(256) void node_denom_k(const float* __restrict__ a_src,
                                                    const float* __restrict__ a_dst,
                                                    const float* __restrict__ mmax,
                                                    float* __restrict__ denom,
                                                    int total) {
  int i = blockIdx.x * blockDim.x + threadIdx.x;
  if (i >= total) return;
  float e_self = lrelu(a_src[i] + a_dst[i]);
  denom[i] = expf(e_self - mmax[i]);
}

// ------------- edge pass 2: segment sum of exp; store numerators p -------------
__global__ __launch_bounds__(256) void edge_sum_k(const int* __restrict__ src,
                                                  const int* __restrict__ dst,
                                                  const float* __restrict__ a_src,
                                                  const float* __restrict__ a_dst,
                                                  const float* __restrict__ mmax,
                                                  float* __restrict__ denom,
                                                  float* __restrict__ p,
                                                  int E) {
  int e = blockIdx.x * blockDim.x + threadIdx.x;
  if (e >= E) return;
  int s = src[e], d = dst[e];
  float4 as4 = *reinterpret_cast<const float4*>(a_src + (size_t)s * 4);
  float4 ad4 = *reinterpret_cast<const float4*>(a_dst + (size_t)d * 4);
  float4 m4  = *reinterpret_cast<const float4*>(mmax  + (size_t)d * 4);
  float4 pv;
  pv.x = expf(lrelu(as4.x + ad4.x) - m4.x);
  pv.y = expf(lrelu(as4.y + ad4.y) - m4.y);
  pv.z = expf(lrelu(as4.z + ad4.z) - m4.z);
  pv.w = expf(lrelu(as4.w + ad4.w) - m4.w);
  *reinterpret_cast<float4*>(p + (size_t)e * 4) = pv;
  atomicAdd(&denom[(size_t)d * 4 + 0], pv.x);
  atomicAdd(&denom[(size_t)d * 4 + 1], pv.y);
  atomicAdd(&denom[(size_t)d * 4 + 2], pv.z);
  atomicAdd(&denom[(size_t)d * 4 + 3], pv.w);
}

// ------------- invert denominators once -------------
__global__ __launch_bounds__(256) void node_rcp_k(float* __restrict__ denom, int total) {
  int i = blockIdx.x * blockDim.x + threadIdx.x;
  if (i >= total) return;
  denom[i] = 1.f / (denom[i] + EPSV);
}

// ------------- edge pass 3: message aggregation (wave per edge) -------------
__global__ __launch_bounds__(256) void edge_agg_k(const int* __restrict__ src,
                                                  const int* __restrict__ dst,
                                                  const float* __restrict__ p,
                                                  const float* __restrict__ rdn,
                                                  const unsigned short* __restrict__ hb16,
                                                  float* __restrict__ acc,
                                                  int E) {
  int wid  = (blockIdx.x * blockDim.x + threadIdx.x) >> 6;
  int lane = threadIdx.x & 63;
  if (wid >= E) return;
  int s = src[wid], d = dst[wid];
  float4 p4 = *reinterpret_cast<const float4*>(p   + (size_t)wid * 4);
  float4 r4 = *reinterpret_cast<const float4*>(rdn + (size_t)d * 4);
  float al0 = p4.x * r4.x, al1 = p4.y * r4.y, al2 = p4.z * r4.z, al3 = p4.w * r4.w;
  ushort4 hv = *reinterpret_cast<const ushort4*>(hb16 + (size_t)s * HC + lane * 4);
  const unsigned short* hvp = reinterpret_cast<const unsigned short*>(&hv);
  float sum = al0 * bf2f(hvp[0]) + al1 * bf2f(hvp[1]) + al2 * bf2f(hvp[2]) + al3 * bf2f(hvp[3]);
  atomicAdd(&acc[(size_t)d * CH + lane], sum);
}

// ------------- finalize: self msg + mean heads + bias + relu (+log_softmax) -------------
__global__ __launch_bounds__(256) void finalize_k(const float* __restrict__ a_src,
                                                  const float* __restrict__ a_dst,
                                                  const float* __restrict__ mmax,
                                                  const float* __restrict__ rdn,
                                                  const float* __restrict__ hbuf,
                                                  const float* __restrict__ acc,
                                                  const float* __restrict__ bias,
                                                  float* __restrict__ outp,
                                                  int N, int do_lsm) {
  int wid  = (blockIdx.x * blockDim.x + threadIdx.x) >> 6;
  int lane = threadIdx.x & 63;
  if (wid >= N) return;
  float4 as4 = *reinterpret_cast<const float4*>(a_src + (size_t)wid * 4);
  float4 ad4 = *reinterpret_cast<const float4*>(a_dst + (size_t)wid * 4);
  float4 m4  = *reinterpret_cast<const float4*>(mmax  + (size_t)wid * 4);
  float4 r4  = *reinterpret_cast<const float4*>(rdn   + (size_t)wid * 4);
  float al0 = expf(lrelu(as4.x + ad4.x) - m4.x) * r4.x;
  float al1 = expf(lrelu(as4.y + ad4.y) - m4.y) * r4.y;
  float al2 = expf(lrelu(as4.z + ad4.z) - m4.z) * r4.z;
  float al3 = expf(lrelu(as4.w + ad4.w) - m4.w) * r4.w;
  const float* hr = hbuf + (size_t)wid * HC;
  float sum = acc[(size_t)wid * CH + lane]
            + al0 * hr[lane] + al1 * hr[CH + lane]
            + al2 * hr[2 * CH + lane] + al3 * hr[3 * CH + lane];
  float v = sum * 0.25f + bias[lane];
  v = fmaxf(v, 0.f);
  if (do_lsm) {
    float mx = v;
    #pragma unroll
    for (int off = 32; off > 0; off >>= 1) mx = fmaxf(mx, __shfl_xor(mx, off));
    float ex = expf(v - mx);
    float sm = ex;
    #pragma unroll
    for (int off = 32; off > 0; off >>= 1) sm += __shfl_xor(sm, off);
    outp[(size_t)wid * CH + lane] = v - mx - logf(sm);
  } else {
    outp[(size_t)wid * CH + lane] = v;
  }
}

extern "C" void kernel_launch(void* const* d_in, const int* in_sizes, int n_in,
                              void* d_out, int out_size, void* d_ws, size_t ws_size,
                              hipStream_t stream) {
  const float* x0 = (const float*)d_in[0];
  const int*   ei = (const int*)d_in[1];
  int N = in_sizes[0] / HC;   // 50000
  int E = in_sizes[1] / 2;    // 800000
  const int* srcp = ei;
  const int* dstp = ei + E;

  const float* W[3]  = {(const float*)d_in[2], (const float*)d_in[6],  (const float*)d_in[10]};
  const float* AS[3] = {(const float*)d_in[3], (const float*)d_in[7],  (const float*)d_in[11]};
  const float* AD[3] = {(const float*)d_in[4], (const float*)d_in[8],  (const float*)d_in[12]};
  const float* BI[3] = {(const float*)d_in[5], (const float*)d_in[9],  (const float*)d_in[13]};
  int Kdim[3] = {256, 64, 64};

  char* ws = (char*)d_ws;
  size_t off = 0;
  auto alloc = [&](size_t bytes) {
    void* p = ws + off;
    off += (bytes + 255) & ~(size_t)255;
    return p;
  };
  float*          hbuf = (float*)alloc((size_t)N * HC * 4);       // 51.2 MB
  float*          acc  = (float*)alloc((size_t)N * CH * 4);       // 12.8 MB
  float*          xbuf = (float*)alloc((size_t)E * 4 * 4);        // 12.8 MB (aliases p)
  unsigned short* hb16 = (unsigned short*)alloc((size_t)N * HC * 2); // 25.6 MB
  float*          a_s  = (float*)alloc((size_t)N * 4 * 4);
  float*          a_d  = (float*)alloc((size_t)N * 4 * 4);
  float*          mm   = (float*)alloc((size_t)N * 4 * 4);
  float*          dn   = (float*)alloc((size_t)N * 4 * 4);
  float*          p    = xbuf;  // alias: xbuf dead between gemm-read and finalize-write

  const float* xin = x0;
  for (int L = 0; L < 3; ++L) {
    int K = Kdim[L];
    dim3 ggrid((N + 63) / 64, 4);
    gemm_k<<<ggrid, 256, 0, stream>>>(xin, W[L], hbuf, N, K);
    node_att_k<<<(N + 3) / 4, 256, 0, stream>>>(hbuf, AS[L], AD[L], a_s, a_d, mm, acc, hb16, N);
    edge_max_k<<<(E + 255) / 256, 256, 0, stream>>>(srcp, dstp, a_s, a_d, mm, E);
    node_denom_k<<<(N * 4 + 255) / 256, 256, 0, stream>>>(a_s, a_d, mm, dn, N * 4);
    edge_sum_k<<<(E + 255) / 256, 256, 0, stream>>>(srcp, dstp, a_s, a_d, mm, dn, p, E);
    node_rcp_k<<<(N * 4 + 255) / 256, 256, 0, stream>>>(dn, N * 4);
    edge_agg_k<<<(E + 3) / 4, 256, 0, stream>>>(srcp, dstp, p, dn, hb16, acc, E);
    float* outp = (L == 2) ? (float*)d_out : xbuf;
    finalize_k<<<(N + 3) / 4, 256, 0, stream>>>(a_s, a_d, mm, dn, hbuf, acc, BI[L], outp, N, (L == 2) ? 1 : 0);
    xin = xbuf;
  }
}

// Round 3
// 658.514 us; speedup vs baseline: 2.7686x; 2.6084x over previous
//
#include <hip/hip_runtime.h>
#include <hip/hip_bf16.h>
#include <math.h>
#include <stdint.h>

#define HEADS 4
#define CH 64          // channels per head
#define HC 256         // HEADS*CH
#define NEG 0.2f
#define EPSV 1e-16f

__device__ __forceinline__ float lrelu(float x) { return x > 0.f ? x : NEG * x; }

__device__ __forceinline__ unsigned short f2bf(float f) {
  __hip_bfloat16 b = __float2bfloat16(f);   // RNE
  return *reinterpret_cast<unsigned short*>(&b);
}
__device__ __forceinline__ float bf2f(unsigned short u) {
  return __uint_as_float((unsigned)u << 16);
}

// ---------------- GEMM: C[M,256] = A[M,K] x B[K,256], f32 ----------------
__global__ __launch_bounds__(256) void gemm_k(const float* __restrict__ A,
                                              const float* __restrict__ B,
                                              float* __restrict__ C,
                                              int M, int K) {
  const int BM = 64, BN = 64, BK = 16;
  __shared__ float As[BK][BM + 4];
  __shared__ float Bs[BK][BN];
  int bm = blockIdx.x * BM, bn = blockIdx.y * BN;
  int tid = threadIdx.x;
  int tx = tid & 15, ty = tid >> 4;
  float acc[4][4] = {};
  for (int k0 = 0; k0 < K; k0 += BK) {
    {
      int r  = tid >> 2;
      int kq = (tid & 3) << 2;
      int gr = bm + r;
      float4 v = make_float4(0.f, 0.f, 0.f, 0.f);
      if (gr < M) v = *reinterpret_cast<const float4*>(A + (size_t)gr * K + k0 + kq);
      As[kq + 0][r] = v.x; As[kq + 1][r] = v.y; As[kq + 2][r] = v.z; As[kq + 3][r] = v.w;
    }
    {
      int kk = tid >> 6;
      int c  = tid & 63;
      #pragma unroll
      for (int q = 0; q < 4; ++q)
        Bs[kk * 4 + q][c] = B[(size_t)(k0 + kk * 4 + q) * HC + bn + c];
    }
    __syncthreads();
    #pragma unroll
    for (int kk = 0; kk < BK; ++kk) {
      float4 av = *reinterpret_cast<const float4*>(&As[kk][ty * 4]);
      float4 bv = *reinterpret_cast<const float4*>(&Bs[kk][tx * 4]);
      float ar[4] = {av.x, av.y, av.z, av.w};
      float br[4] = {bv.x, bv.y, bv.z, bv.w};
      #pragma unroll
      for (int i = 0; i < 4; ++i)
        #pragma unroll
        for (int j = 0; j < 4; ++j)
          acc[i][j] += ar[i] * br[j];
    }
    __syncthreads();
  }
  #pragma unroll
  for (int i = 0; i < 4; ++i) {
    int gr = bm + ty * 4 + i;
    if (gr < M) {
      float4 o = make_float4(acc[i][0], acc[i][1], acc[i][2], acc[i][3]);
      *reinterpret_cast<float4*>(C + (size_t)gr * HC + bn + tx * 4) = o;
    }
  }
}

// ================= CSR build (once per call) =================
__global__ __launch_bounds__(256) void zero2_k(int* __restrict__ a, int* __restrict__ b, int n) {
  int i = blockIdx.x * blockDim.x + threadIdx.x;
  if (i < n) { a[i] = 0; b[i] = 0; }
}

__global__ __launch_bounds__(256) void hist_k(const int* __restrict__ dst, int* __restrict__ count, int E) {
  int e = blockIdx.x * blockDim.x + threadIdx.x;
  if (e < E) atomicAdd(&count[dst[e]], 1);
}

// block-level exclusive scan (512 elems/block), Hillis-Steele in LDS
__global__ __launch_bounds__(512) void scan1_k(const int* __restrict__ count,
                                               int* __restrict__ rp,
                                               int* __restrict__ bsum, int n) {
  __shared__ int sh[512];
  int tx = threadIdx.x;
  int i = blockIdx.x * 512 + tx;
  int v = (i < n) ? count[i] : 0;
  sh[tx] = v;
  __syncthreads();
  #pragma unroll
  for (int off = 1; off < 512; off <<= 1) {
    int t = (tx >= off) ? sh[tx - off] : 0;
    __syncthreads();
    sh[tx] += t;
    __syncthreads();
  }
  if (i < n) rp[i] = sh[tx] - v;          // exclusive
  if (tx == 511) bsum[blockIdx.x] = sh[511];
}

__global__ __launch_bounds__(128) void scan2_k(int* __restrict__ bsum, int nb) {
  __shared__ int sh[128];
  int tx = threadIdx.x;
  int v = (tx < nb) ? bsum[tx] : 0;
  sh[tx] = v;
  __syncthreads();
  #pragma unroll
  for (int off = 1; off < 128; off <<= 1) {
    int t = (tx >= off) ? sh[tx - off] : 0;
    __syncthreads();
    sh[tx] += t;
    __syncthreads();
  }
  if (tx < nb) bsum[tx] = sh[tx] - v;      // exclusive
}

__global__ __launch_bounds__(512) void scan3_k(int* __restrict__ rp, const int* __restrict__ bsum,
                                               int n, int E) {
  int i = blockIdx.x * 512 + threadIdx.x;
  if (i < n) rp[i] += bsum[blockIdx.x];
  if (i == 0) rp[n] = E;
}

__global__ __launch_bounds__(256) void scatter_k(const int* __restrict__ src, const int* __restrict__ dst,
                                                 const int* __restrict__ rp, int* __restrict__ cursor,
                                                 int* __restrict__ csr_src, int E) {
  int e = blockIdx.x * blockDim.x + threadIdx.x;
  if (e >= E) return;
  int d = dst[e];
  int pos = rp[d] + atomicAdd(&cursor[d], 1);
  csr_src[pos] = src[e];
}

// ------------- per-node: a_src/a_dst dots + bf16 channel-major copy -------------
__global__ __launch_bounds__(256) void node_att_k(const float* __restrict__ hbuf,
                                                  const float* __restrict__ att_s,
                                                  const float* __restrict__ att_d,
                                                  float* __restrict__ a_src,
                                                  float* __restrict__ a_dst,
                                                  unsigned short* __restrict__ hb16,
                                                  int N) {
  int wid  = (blockIdx.x * blockDim.x + threadIdx.x) >> 6;
  int lane = threadIdx.x & 63;
  if (wid >= N) return;
  const float* hr = hbuf + (size_t)wid * HC;
  float as_h[HEADS], ad_h[HEADS];
  ushort4 pack;
  unsigned short* pk = reinterpret_cast<unsigned short*>(&pack);
  #pragma unroll
  for (int hh = 0; hh < HEADS; ++hh) {
    float hv = hr[hh * CH + lane];
    pk[hh] = f2bf(hv);
    float ps = hv * att_s[hh * CH + lane];
    float pd = hv * att_d[hh * CH + lane];
    #pragma unroll
    for (int off = 32; off > 0; off >>= 1) {
      ps += __shfl_xor(ps, off);
      pd += __shfl_xor(pd, off);
    }
    as_h[hh] = ps; ad_h[hh] = pd;
  }
  *reinterpret_cast<ushort4*>(hb16 + (size_t)wid * HC + lane * 4) = pack;
  if (lane == 0) {
    #pragma unroll
    for (int hh = 0; hh < HEADS; ++hh) {
      a_src[(size_t)wid * 4 + hh] = as_h[hh];
      a_dst[(size_t)wid * 4 + hh] = ad_h[hh];
    }
  }
}

// ------------- fused segment softmax over CSR: max, exp-sum, rcp, self terms -------------
// 16 lanes per node, 16 nodes per 256-block. pbuf[j][4] gets exp(e - m) in CSR order.
__global__ __launch_bounds__(256) void att_soft_k(const int* __restrict__ rp,
                                                  const int* __restrict__ csr_src,
                                                  const float* __restrict__ a_src,
                                                  const float* __restrict__ a_dst,
                                                  float* __restrict__ pbuf,
                                                  float* __restrict__ rdn,
                                                  float* __restrict__ selfp,
                                                  int N) {
  int node = blockIdx.x * 16 + (threadIdx.x >> 4);
  int sub  = threadIdx.x & 15;
  if (node >= N) return;
  int rs = rp[node], re = rp[node + 1];
  float4 ad4 = *reinterpret_cast<const float4*>(a_dst + (size_t)node * 4);
  float4 asf = *reinterpret_cast<const float4*>(a_src + (size_t)node * 4);
  float es0 = lrelu(asf.x + ad4.x), es1 = lrelu(asf.y + ad4.y);
  float es2 = lrelu(asf.z + ad4.z), es3 = lrelu(asf.w + ad4.w);
  float m0 = es0, m1 = es1, m2 = es2, m3 = es3;
  // phase 1: compute e, store raw e, track max
  for (int j = rs + sub; j < re; j += 16) {
    int s = csr_src[j];
    float4 as4 = *reinterpret_cast<const float4*>(a_src + (size_t)s * 4);
    float4 e4;
    e4.x = lrelu(as4.x + ad4.x); e4.y = lrelu(as4.y + ad4.y);
    e4.z = lrelu(as4.z + ad4.z); e4.w = lrelu(as4.w + ad4.w);
    *reinterpret_cast<float4*>(pbuf + (size_t)j * 4) = e4;
    m0 = fmaxf(m0, e4.x); m1 = fmaxf(m1, e4.y);
    m2 = fmaxf(m2, e4.z); m3 = fmaxf(m3, e4.w);
  }
  #pragma unroll
  for (int off = 8; off > 0; off >>= 1) {
    m0 = fmaxf(m0, __shfl_xor(m0, off, 16));
    m1 = fmaxf(m1, __shfl_xor(m1, off, 16));
    m2 = fmaxf(m2, __shfl_xor(m2, off, 16));
    m3 = fmaxf(m3, __shfl_xor(m3, off, 16));
  }
  // phase 2: p = exp(e - m), store, sum
  float d0 = 0.f, d1 = 0.f, d2 = 0.f, d3 = 0.f;
  for (int j = rs + sub; j < re; j += 16) {
    float4 e4 = *reinterpret_cast<const float4*>(pbuf + (size_t)j * 4);
    float4 pv;
    pv.x = expf(e4.x - m0); pv.y = expf(e4.y - m1);
    pv.z = expf(e4.z - m2); pv.w = expf(e4.w - m3);
    *reinterpret_cast<float4*>(pbuf + (size_t)j * 4) = pv;
    d0 += pv.x; d1 += pv.y; d2 += pv.z; d3 += pv.w;
  }
  #pragma unroll
  for (int off = 8; off > 0; off >>= 1) {
    d0 += __shfl_xor(d0, off, 16);
    d1 += __shfl_xor(d1, off, 16);
    d2 += __shfl_xor(d2, off, 16);
    d3 += __shfl_xor(d3, off, 16);
  }
  float sp0 = expf(es0 - m0), sp1 = expf(es1 - m1);
  float sp2 = expf(es2 - m2), sp3 = expf(es3 - m3);
  d0 += sp0; d1 += sp1; d2 += sp2; d3 += sp3;
  if (sub == 0) {
    float4 r4 = make_float4(1.f / (d0 + EPSV), 1.f / (d1 + EPSV),
                            1.f / (d2 + EPSV), 1.f / (d3 + EPSV));
    float4 s4 = make_float4(sp0, sp1, sp2, sp3);
    *reinterpret_cast<float4*>(rdn   + (size_t)node * 4) = r4;
    *reinterpret_cast<float4*>(selfp + (size_t)node * 4) = s4;
  }
}

// ------------- gather-aggregate + finalize (wave per node, lane = channel) -------------
__global__ __launch_bounds__(256) void agg_fin_k(const int* __restrict__ rp,
                                                 const int* __restrict__ csr_src,
                                                 const float* __restrict__ pbuf,
                                                 const float* __restrict__ rdn,
                                                 const float* __restrict__ selfp,
                                                 const unsigned short* __restrict__ hb16,
                                                 const float* __restrict__ hbuf,
                                                 const float* __restrict__ bias,
                                                 float* __restrict__ outp,
                                                 int N, int do_lsm) {
  int wid  = (blockIdx.x * blockDim.x + threadIdx.x) >> 6;
  int lane = threadIdx.x & 63;
  if (wid >= N) return;
  int rs = rp[wid], re = rp[wid + 1];
  float4 r4 = *reinterpret_cast<const float4*>(rdn   + (size_t)wid * 4);
  float4 sp = *reinterpret_cast<const float4*>(selfp + (size_t)wid * 4);
  // self message in f32 precision
  const float* hrow = hbuf + (size_t)wid * HC;
  float sum = sp.x * r4.x * hrow[lane]
            + sp.y * r4.y * hrow[CH + lane]
            + sp.z * r4.z * hrow[2 * CH + lane]
            + sp.w * r4.w * hrow[3 * CH + lane];
  for (int j = rs; j < re; ++j) {
    int s = csr_src[j];
    float4 p4 = *reinterpret_cast<const float4*>(pbuf + (size_t)j * 4);
    ushort4 hv = *reinterpret_cast<const ushort4*>(hb16 + (size_t)s * HC + lane * 4);
    sum += p4.x * r4.x * bf2f(hv.x) + p4.y * r4.y * bf2f(hv.y)
         + p4.z * r4.z * bf2f(hv.z) + p4.w * r4.w * bf2f(hv.w);
  }
  float v = sum * 0.25f + bias[lane];
  v = fmaxf(v, 0.f);
  if (do_lsm) {
    float mx = v;
    #pragma unroll
    for (int off = 32; off > 0; off >>= 1) mx = fmaxf(mx, __shfl_xor(mx, off));
    float ex = expf(v - mx);
    float sm = ex;
    #pragma unroll
    for (int off = 32; off > 0; off >>= 1) sm += __shfl_xor(sm, off);
    outp[(size_t)wid * CH + lane] = v - mx - logf(sm);
  } else {
    outp[(size_t)wid * CH + lane] = v;
  }
}

extern "C" void kernel_launch(void* const* d_in, const int* in_sizes, int n_in,
                              void* d_out, int out_size, void* d_ws, size_t ws_size,
                              hipStream_t stream) {
  const float* x0 = (const float*)d_in[0];
  const int*   ei = (const int*)d_in[1];
  int N = in_sizes[0] / HC;   // 50000
  int E = in_sizes[1] / 2;    // 800000
  const int* srcp = ei;
  const int* dstp = ei + E;

  const float* W[3]  = {(const float*)d_in[2], (const float*)d_in[6],  (const float*)d_in[10]};
  const float* AS[3] = {(const float*)d_in[3], (const float*)d_in[7],  (const float*)d_in[11]};
  const float* AD[3] = {(const float*)d_in[4], (const float*)d_in[8],  (const float*)d_in[12]};
  const float* BI[3] = {(const float*)d_in[5], (const float*)d_in[9],  (const float*)d_in[13]};
  int Kdim[3] = {256, 64, 64};

  char* ws = (char*)d_ws;
  size_t off = 0;
  auto alloc = [&](size_t bytes) {
    void* p = ws + off;
    off += (bytes + 255) & ~(size_t)255;
    return p;
  };
  float*          hbuf    = (float*)alloc((size_t)N * HC * 4);          // 51.2 MB
  unsigned short* hb16    = (unsigned short*)alloc((size_t)N * HC * 2); // 25.6 MB
  float*          xbuf    = (float*)alloc((size_t)N * CH * 4);          // 12.8 MB
  float*          pbuf    = (float*)alloc((size_t)E * 4 * 4);           // 12.8 MB
  float*          a_s     = (float*)alloc((size_t)N * 4 * 4);
  float*          a_d     = (float*)alloc((size_t)N * 4 * 4);
  float*          rdn     = (float*)alloc((size_t)N * 4 * 4);
  float*          selfp   = (float*)alloc((size_t)N * 4 * 4);
  int*            rowp    = (int*)alloc((size_t)(N + 1) * 4);
  int*            cursor  = (int*)alloc((size_t)N * 4);
  int*            csr_src = (int*)alloc((size_t)E * 4);                 // 3.2 MB
  int*            bsum    = (int*)alloc(512 * 4);

  // ---- build CSR by destination (once; reused by all 3 layers) ----
  int nb = (N + 511) / 512;
  zero2_k<<<(N + 255) / 256, 256, 0, stream>>>(cursor, rowp, N);
  hist_k<<<(E + 255) / 256, 256, 0, stream>>>(dstp, rowp, E);  // rowp as counts
  // scan counts -> exclusive prefix. Use cursor as scratch? No: scan in place:
  scan1_k<<<nb, 512, 0, stream>>>(rowp, rowp, bsum, N);        // rowp: counts -> excl (in place safe: each i reads own then writes own)
  scan2_k<<<1, 128, 0, stream>>>(bsum, nb);
  scan3_k<<<nb, 512, 0, stream>>>(rowp, bsum, N, E);
  scatter_k<<<(E + 255) / 256, 256, 0, stream>>>(srcp, dstp, rowp, cursor, csr_src, E);

  const float* xin = x0;
  for (int L = 0; L < 3; ++L) {
    int K = Kdim[L];
    dim3 ggrid((N + 63) / 64, 4);
    gemm_k<<<ggrid, 256, 0, stream>>>(xin, W[L], hbuf, N, K);
    node_att_k<<<(N + 3) / 4, 256, 0, stream>>>(hbuf, AS[L], AD[L], a_s, a_d, hb16, N);
    att_soft_k<<<(N + 15) / 16, 256, 0, stream>>>(rowp, csr_src, a_s, a_d, pbuf, rdn, selfp, N);
    float* outp = (L == 2) ? (float*)d_out : xbuf;
    agg_fin_k<<<(N + 3) / 4, 256, 0, stream>>>(rowp, csr_src, pbuf, rdn, selfp, hb16, hbuf, BI[L], outp, N, (L == 2) ? 1 : 0);
    xin = xbuf;
  }
}

// Round 4
// 575.155 us; speedup vs baseline: 3.1699x; 1.1449x over previous
//
#include <hip/hip_runtime.h>
#include <hip/hip_bf16.h>
#include <math.h>
#include <stdint.h>

#define HEADS 4
#define CH 64          // channels per head
#define HC 256         // HEADS*CH
#define NEG 0.2f
#define EPSV 1e-16f

__device__ __forceinline__ float lrelu(float x) { return x > 0.f ? x : NEG * x; }

__device__ __forceinline__ unsigned short f2bf(float f) {
  __hip_bfloat16 b = __float2bfloat16(f);   // RNE
  return *reinterpret_cast<unsigned short*>(&b);
}
__device__ __forceinline__ float bf2f(unsigned short u) {
  return __uint_as_float((unsigned)u << 16);
}

// ---------------- GEMM: C[M,256] = A[M,K] x B[K,256], f32 ----------------
__global__ __launch_bounds__(256) void gemm_k(const float* __restrict__ A,
                                              const float* __restrict__ B,
                                              float* __restrict__ C,
                                              int M, int K) {
  const int BM = 64, BN = 64, BK = 16;
  __shared__ float As[BK][BM + 4];
  __shared__ float Bs[BK][BN];
  int bm = blockIdx.x * BM, bn = blockIdx.y * BN;
  int tid = threadIdx.x;
  int tx = tid & 15, ty = tid >> 4;
  float acc[4][4] = {};
  for (int k0 = 0; k0 < K; k0 += BK) {
    {
      int r  = tid >> 2;
      int kq = (tid & 3) << 2;
      int gr = bm + r;
      float4 v = make_float4(0.f, 0.f, 0.f, 0.f);
      if (gr < M) v = *reinterpret_cast<const float4*>(A + (size_t)gr * K + k0 + kq);
      As[kq + 0][r] = v.x; As[kq + 1][r] = v.y; As[kq + 2][r] = v.z; As[kq + 3][r] = v.w;
    }
    {
      int kk = tid >> 6;
      int c  = tid & 63;
      #pragma unroll
      for (int q = 0; q < 4; ++q)
        Bs[kk * 4 + q][c] = B[(size_t)(k0 + kk * 4 + q) * HC + bn + c];
    }
    __syncthreads();
    #pragma unroll
    for (int kk = 0; kk < BK; ++kk) {
      float4 av = *reinterpret_cast<const float4*>(&As[kk][ty * 4]);
      float4 bv = *reinterpret_cast<const float4*>(&Bs[kk][tx * 4]);
      float ar[4] = {av.x, av.y, av.z, av.w};
      float br[4] = {bv.x, bv.y, bv.z, bv.w};
      #pragma unroll
      for (int i = 0; i < 4; ++i)
        #pragma unroll
        for (int j = 0; j < 4; ++j)
          acc[i][j] += ar[i] * br[j];
    }
    __syncthreads();
  }
  #pragma unroll
  for (int i = 0; i < 4; ++i) {
    int gr = bm + ty * 4 + i;
    if (gr < M) {
      float4 o = make_float4(acc[i][0], acc[i][1], acc[i][2], acc[i][3]);
      *reinterpret_cast<float4*>(C + (size_t)gr * HC + bn + tx * 4) = o;
    }
  }
}

// ================= CSR build (once per call) =================
__global__ __launch_bounds__(256) void zero2_k(int* __restrict__ a, int* __restrict__ b, int n) {
  int i = blockIdx.x * blockDim.x + threadIdx.x;
  if (i < n) { a[i] = 0; b[i] = 0; }
}

__global__ __launch_bounds__(256) void hist_k(const int* __restrict__ dst, int* __restrict__ count, int E) {
  int e = blockIdx.x * blockDim.x + threadIdx.x;
  if (e < E) atomicAdd(&count[dst[e]], 1);
}

__global__ __launch_bounds__(512) void scan1_k(const int* __restrict__ count,
                                               int* __restrict__ rp,
                                               int* __restrict__ bsum, int n) {
  __shared__ int sh[512];
  int tx = threadIdx.x;
  int i = blockIdx.x * 512 + tx;
  int v = (i < n) ? count[i] : 0;
  sh[tx] = v;
  __syncthreads();
  #pragma unroll
  for (int off = 1; off < 512; off <<= 1) {
    int t = (tx >= off) ? sh[tx - off] : 0;
    __syncthreads();
    sh[tx] += t;
    __syncthreads();
  }
  if (i < n) rp[i] = sh[tx] - v;          // exclusive
  if (tx == 511) bsum[blockIdx.x] = sh[511];
}

__global__ __launch_bounds__(128) void scan2_k(int* __restrict__ bsum, int nb) {
  __shared__ int sh[128];
  int tx = threadIdx.x;
  int v = (tx < nb) ? bsum[tx] : 0;
  sh[tx] = v;
  __syncthreads();
  #pragma unroll
  for (int off = 1; off < 128; off <<= 1) {
    int t = (tx >= off) ? sh[tx - off] : 0;
    __syncthreads();
    sh[tx] += t;
    __syncthreads();
  }
  if (tx < nb) bsum[tx] = sh[tx] - v;      // exclusive
}

__global__ __launch_bounds__(512) void scan3_k(int* __restrict__ rp, const int* __restrict__ bsum,
                                               int n, int E) {
  int i = blockIdx.x * 512 + threadIdx.x;
  if (i < n) rp[i] += bsum[blockIdx.x];
  if (i == 0) rp[n] = E;
}

__global__ __launch_bounds__(256) void scatter_k(const int* __restrict__ src, const int* __restrict__ dst,
                                                 const int* __restrict__ rp, int* __restrict__ cursor,
                                                 int* __restrict__ csr_src, int E) {
  int e = blockIdx.x * blockDim.x + threadIdx.x;
  if (e >= E) return;
  int d = dst[e];
  int pos = rp[d] + atomicAdd(&cursor[d], 1);
  csr_src[pos] = src[e];
}

// ------------- per-node: a_src/a_dst dots + bf16 channel-major copy -------------
__global__ __launch_bounds__(256) void node_att_k(const float* __restrict__ hbuf,
                                                  const float* __restrict__ att_s,
                                                  const float* __restrict__ att_d,
                                                  float* __restrict__ a_src,
                                                  float* __restrict__ a_dst,
                                                  unsigned short* __restrict__ hb16,
                                                  int N) {
  int wid  = (blockIdx.x * blockDim.x + threadIdx.x) >> 6;
  int lane = threadIdx.x & 63;
  if (wid >= N) return;
  const float* hr = hbuf + (size_t)wid * HC;
  float as_h[HEADS], ad_h[HEADS];
  ushort4 pack;
  unsigned short* pk = reinterpret_cast<unsigned short*>(&pack);
  #pragma unroll
  for (int hh = 0; hh < HEADS; ++hh) {
    float hv = hr[hh * CH + lane];
    pk[hh] = f2bf(hv);
    float ps = hv * att_s[hh * CH + lane];
    float pd = hv * att_d[hh * CH + lane];
    #pragma unroll
    for (int off = 32; off > 0; off >>= 1) {
      ps += __shfl_xor(ps, off);
      pd += __shfl_xor(pd, off);
    }
    as_h[hh] = ps; ad_h[hh] = pd;
  }
  *reinterpret_cast<ushort4*>(hb16 + (size_t)wid * HC + lane * 4) = pack;
  if (lane == 0) {
    #pragma unroll
    for (int hh = 0; hh < HEADS; ++hh) {
      a_src[(size_t)wid * 4 + hh] = as_h[hh];
      a_dst[(size_t)wid * 4 + hh] = ad_h[hh];
    }
  }
}

// ------------- fused segment softmax over CSR: max, exp-sum, rcp, self terms -------------
__global__ __launch_bounds__(256) void att_soft_k(const int* __restrict__ rp,
                                                  const int* __restrict__ csr_src,
                                                  const float* __restrict__ a_src,
                                                  const float* __restrict__ a_dst,
                                                  float* __restrict__ pbuf,
                                                  float* __restrict__ rdn,
                                                  float* __restrict__ selfp,
                                                  int N) {
  int node = blockIdx.x * 16 + (threadIdx.x >> 4);
  int sub  = threadIdx.x & 15;
  if (node >= N) return;
  int rs = rp[node], re = rp[node + 1];
  float4 ad4 = *reinterpret_cast<const float4*>(a_dst + (size_t)node * 4);
  float4 asf = *reinterpret_cast<const float4*>(a_src + (size_t)node * 4);
  float es0 = lrelu(asf.x + ad4.x), es1 = lrelu(asf.y + ad4.y);
  float es2 = lrelu(asf.z + ad4.z), es3 = lrelu(asf.w + ad4.w);
  float m0 = es0, m1 = es1, m2 = es2, m3 = es3;
  for (int j = rs + sub; j < re; j += 16) {
    int s = csr_src[j];
    float4 as4 = *reinterpret_cast<const float4*>(a_src + (size_t)s * 4);
    float4 e4;
    e4.x = lrelu(as4.x + ad4.x); e4.y = lrelu(as4.y + ad4.y);
    e4.z = lrelu(as4.z + ad4.z); e4.w = lrelu(as4.w + ad4.w);
    *reinterpret_cast<float4*>(pbuf + (size_t)j * 4) = e4;
    m0 = fmaxf(m0, e4.x); m1 = fmaxf(m1, e4.y);
    m2 = fmaxf(m2, e4.z); m3 = fmaxf(m3, e4.w);
  }
  #pragma unroll
  for (int off = 8; off > 0; off >>= 1) {
    m0 = fmaxf(m0, __shfl_xor(m0, off, 16));
    m1 = fmaxf(m1, __shfl_xor(m1, off, 16));
    m2 = fmaxf(m2, __shfl_xor(m2, off, 16));
    m3 = fmaxf(m3, __shfl_xor(m3, off, 16));
  }
  float d0 = 0.f, d1 = 0.f, d2 = 0.f, d3 = 0.f;
  for (int j = rs + sub; j < re; j += 16) {
    float4 e4 = *reinterpret_cast<const float4*>(pbuf + (size_t)j * 4);
    float4 pv;
    pv.x = expf(e4.x - m0); pv.y = expf(e4.y - m1);
    pv.z = expf(e4.z - m2); pv.w = expf(e4.w - m3);
    *reinterpret_cast<float4*>(pbuf + (size_t)j * 4) = pv;
    d0 += pv.x; d1 += pv.y; d2 += pv.z; d3 += pv.w;
  }
  #pragma unroll
  for (int off = 8; off > 0; off >>= 1) {
    d0 += __shfl_xor(d0, off, 16);
    d1 += __shfl_xor(d1, off, 16);
    d2 += __shfl_xor(d2, off, 16);
    d3 += __shfl_xor(d3, off, 16);
  }
  float sp0 = expf(es0 - m0), sp1 = expf(es1 - m1);
  float sp2 = expf(es2 - m2), sp3 = expf(es3 - m3);
  d0 += sp0; d1 += sp1; d2 += sp2; d3 += sp3;
  if (sub == 0) {
    float4 r4 = make_float4(1.f / (d0 + EPSV), 1.f / (d1 + EPSV),
                            1.f / (d2 + EPSV), 1.f / (d3 + EPSV));
    float4 s4 = make_float4(sp0, sp1, sp2, sp3);
    *reinterpret_cast<float4*>(rdn   + (size_t)node * 4) = r4;
    *reinterpret_cast<float4*>(selfp + (size_t)node * 4) = s4;
  }
}

// ------------- gather-aggregate + finalize (wave per node, lane = channel) -------------
// 4x unrolled gather for memory-level parallelism; per-head accumulators with
// reciprocal-denominator factored out of the loop.
__global__ __launch_bounds__(256) void agg_fin_k(const int* __restrict__ rp,
                                                 const int* __restrict__ csr_src,
                                                 const float* __restrict__ pbuf,
                                                 const float* __restrict__ rdn,
                                                 const float* __restrict__ selfp,
                                                 const unsigned short* __restrict__ hb16,
                                                 const float* __restrict__ hbuf,
                                                 const float* __restrict__ bias,
                                                 float* __restrict__ outp,
                                                 int N, int do_lsm) {
  int wid  = (blockIdx.x * blockDim.x + threadIdx.x) >> 6;
  int lane = threadIdx.x & 63;
  if (wid >= N) return;
  int rs = rp[wid], re = rp[wid + 1];
  float4 r4 = *reinterpret_cast<const float4*>(rdn   + (size_t)wid * 4);
  float4 sp = *reinterpret_cast<const float4*>(selfp + (size_t)wid * 4);
  // per-head accumulators (r4 applied once at the end)
  float a0 = 0.f, a1 = 0.f, a2 = 0.f, a3 = 0.f;
  int j = rs;
  for (; j + 4 <= re; j += 4) {
    int s0 = csr_src[j + 0], s1 = csr_src[j + 1];
    int s2 = csr_src[j + 2], s3 = csr_src[j + 3];
    float4 p0 = *reinterpret_cast<const float4*>(pbuf + (size_t)(j + 0) * 4);
    float4 p1 = *reinterpret_cast<const float4*>(pbuf + (size_t)(j + 1) * 4);
    float4 p2 = *reinterpret_cast<const float4*>(pbuf + (size_t)(j + 2) * 4);
    float4 p3 = *reinterpret_cast<const float4*>(pbuf + (size_t)(j + 3) * 4);
    ushort4 h0 = *reinterpret_cast<const ushort4*>(hb16 + (size_t)s0 * HC + lane * 4);
    ushort4 h1 = *reinterpret_cast<const ushort4*>(hb16 + (size_t)s1 * HC + lane * 4);
    ushort4 h2 = *reinterpret_cast<const ushort4*>(hb16 + (size_t)s2 * HC + lane * 4);
    ushort4 h3 = *reinterpret_cast<const ushort4*>(hb16 + (size_t)s3 * HC + lane * 4);
    a0 += p0.x * bf2f(h0.x) + p1.x * bf2f(h1.x) + p2.x * bf2f(h2.x) + p3.x * bf2f(h3.x);
    a1 += p0.y * bf2f(h0.y) + p1.y * bf2f(h1.y) + p2.y * bf2f(h2.y) + p3.y * bf2f(h3.y);
    a2 += p0.z * bf2f(h0.z) + p1.z * bf2f(h1.z) + p2.z * bf2f(h2.z) + p3.z * bf2f(h3.z);
    a3 += p0.w * bf2f(h0.w) + p1.w * bf2f(h1.w) + p2.w * bf2f(h2.w) + p3.w * bf2f(h3.w);
  }
  for (; j < re; ++j) {
    int s = csr_src[j];
    float4 p4 = *reinterpret_cast<const float4*>(pbuf + (size_t)j * 4);
    ushort4 hv = *reinterpret_cast<const ushort4*>(hb16 + (size_t)s * HC + lane * 4);
    a0 += p4.x * bf2f(hv.x); a1 += p4.y * bf2f(hv.y);
    a2 += p4.z * bf2f(hv.z); a3 += p4.w * bf2f(hv.w);
  }
  // self message in f32 precision
  const float* hrow = hbuf + (size_t)wid * HC;
  float sum = (a0 + sp.x * hrow[lane])          * r4.x
            + (a1 + sp.y * hrow[CH + lane])     * r4.y
            + (a2 + sp.z * hrow[2 * CH + lane]) * r4.z
            + (a3 + sp.w * hrow[3 * CH + lane]) * r4.w;
  float v = sum * 0.25f + bias[lane];
  v = fmaxf(v, 0.f);
  if (do_lsm) {
    float mx = v;
    #pragma unroll
    for (int off = 32; off > 0; off >>= 1) mx = fmaxf(mx, __shfl_xor(mx, off));
    float ex = expf(v - mx);
    float sm = ex;
    #pragma unroll
    for (int off = 32; off > 0; off >>= 1) sm += __shfl_xor(sm, off);
    outp[(size_t)wid * CH + lane] = v - mx - logf(sm);
  } else {
    outp[(size_t)wid * CH + lane] = v;
  }
}

extern "C" void kernel_launch(void* const* d_in, const int* in_sizes, int n_in,
                              void* d_out, int out_size, void* d_ws, size_t ws_size,
                              hipStream_t stream) {
  const float* x0 = (const float*)d_in[0];
  const int*   ei = (const int*)d_in[1];
  int N = in_sizes[0] / HC;   // 50000
  int E = in_sizes[1] / 2;    // 800000
  const int* srcp = ei;
  const int* dstp = ei + E;

  const float* W[3]  = {(const float*)d_in[2], (const float*)d_in[6],  (const float*)d_in[10]};
  const float* AS[3] = {(const float*)d_in[3], (const float*)d_in[7],  (const float*)d_in[11]};
  const float* AD[3] = {(const float*)d_in[4], (const float*)d_in[8],  (const float*)d_in[12]};
  const float* BI[3] = {(const float*)d_in[5], (const float*)d_in[9],  (const float*)d_in[13]};
  int Kdim[3] = {256, 64, 64};

  char* ws = (char*)d_ws;
  size_t off = 0;
  auto alloc = [&](size_t bytes) {
    void* p = ws + off;
    off += (bytes + 255) & ~(size_t)255;
    return p;
  };
  float*          hbuf    = (float*)alloc((size_t)N * HC * 4);          // 51.2 MB
  unsigned short* hb16    = (unsigned short*)alloc((size_t)N * HC * 2); // 25.6 MB
  float*          xbuf    = (float*)alloc((size_t)N * CH * 4);          // 12.8 MB
  float*          pbuf    = (float*)alloc((size_t)E * 4 * 4);           // 12.8 MB
  float*          a_s     = (float*)alloc((size_t)N * 4 * 4);
  float*          a_d     = (float*)alloc((size_t)N * 4 * 4);
  float*          rdn     = (float*)alloc((size_t)N * 4 * 4);
  float*          selfp   = (float*)alloc((size_t)N * 4 * 4);
  int*            rowp    = (int*)alloc((size_t)(N + 1) * 4);
  int*            cursor  = (int*)alloc((size_t)N * 4);
  int*            csr_src = (int*)alloc((size_t)E * 4);                 // 3.2 MB
  int*            bsum    = (int*)alloc(512 * 4);

  // ---- build CSR by destination (once; reused by all 3 layers) ----
  int nb = (N + 511) / 512;
  zero2_k<<<(N + 255) / 256, 256, 0, stream>>>(cursor, rowp, N);
  hist_k<<<(E + 255) / 256, 256, 0, stream>>>(dstp, rowp, E);
  scan1_k<<<nb, 512, 0, stream>>>(rowp, rowp, bsum, N);
  scan2_k<<<1, 128, 0, stream>>>(bsum, nb);
  scan3_k<<<nb, 512, 0, stream>>>(rowp, bsum, N, E);
  scatter_k<<<(E + 255) / 256, 256, 0, stream>>>(srcp, dstp, rowp, cursor, csr_src, E);

  const float* xin = x0;
  for (int L = 0; L < 3; ++L) {
    int K = Kdim[L];
    dim3 ggrid((N + 63) / 64, 4);
    gemm_k<<<ggrid, 256, 0, stream>>>(xin, W[L], hbuf, N, K);
    node_att_k<<<(N + 3) / 4, 256, 0, stream>>>(hbuf, AS[L], AD[L], a_s, a_d, hb16, N);
    att_soft_k<<<(N + 15) / 16, 256, 0, stream>>>(rowp, csr_src, a_s, a_d, pbuf, rdn, selfp, N);
    float* outp = (L == 2) ? (float*)d_out : xbuf;
    agg_fin_k<<<(N + 3) / 4, 256, 0, stream>>>(rowp, csr_src, pbuf, rdn, selfp, hb16, hbuf, BI[L], outp, N, (L == 2) ? 1 : 0);
    xin = xbuf;
  }
}

// Round 5
// 446.069 us; speedup vs baseline: 4.0872x; 1.2894x over previous
//
#include <hip/hip_runtime.h>
#include <hip/hip_bf16.h>
#include <math.h>
#include <stdint.h>

#define HEADS 4
#define CH 64          // channels per head
#define HC 256         // HEADS*CH
#define NEG 0.2f
#define EPSV 1e-16f

typedef __attribute__((ext_vector_type(8))) short short8;
typedef __attribute__((ext_vector_type(4))) float f32x4;

__device__ __forceinline__ float lrelu(float x) { return x > 0.f ? x : NEG * x; }

__device__ __forceinline__ unsigned short f2bf(float f) {
  __hip_bfloat16 b = __float2bfloat16(f);   // RNE
  return *reinterpret_cast<unsigned short*>(&b);
}
__device__ __forceinline__ float bf2f(unsigned short u) {
  return __uint_as_float((unsigned)u << 16);
}

// ---------------- weight prep: Wt[n][k] bf16 from W[k][n] f32 ----------------
__global__ __launch_bounds__(256) void wprep_k(const float* __restrict__ W,
                                               unsigned short* __restrict__ Wt,
                                               int K) {
  int i = blockIdx.x * 256 + threadIdx.x;
  if (i >= K * 256) return;
  int k = i >> 8, n = i & 255;
  Wt[(size_t)n * K + k] = f2bf(W[i]);
}

// ---------------- fused MFMA GEMM + attention-dot epilogue ----------------
// C[M,256] = A[M,K] x W[K,256] via bf16 MFMA (f32 accumulate).
// Block: 256 thr = 4 waves; tile 32 rows x 256 cols; wave w owns head w (64 cols).
// Outputs: hb16 channel-major [node][chan][head] bf16, a_src/a_dst [node][4] f32.
__global__ __launch_bounds__(256) void mfma_gat_k(const float* __restrict__ Af,
                                                  const unsigned short* __restrict__ Ab,
                                                  const unsigned short* __restrict__ Wt,
                                                  const float* __restrict__ att_s,
                                                  const float* __restrict__ att_d,
                                                  unsigned short* __restrict__ hb16,
                                                  float* __restrict__ a_src,
                                                  float* __restrict__ a_dst,
                                                  int M, int K, int a_is_f32) {
  __shared__ unsigned short As[32 * 40];    // [row][k] stride 40 (pad)
  __shared__ unsigned short Bs[256 * 40];   // [col][k] stride 40
  __shared__ unsigned short Cs[32 * 258];   // [row][chan*4+head] channel-major

  int tid = threadIdx.x;
  int bm = blockIdx.x * 32;
  int w = tid >> 6, l = tid & 63;
  int lr = l & 15, lk = l >> 4;             // fragment row/col and k-part
  int row_s = tid >> 3, seg = tid & 7;      // staging coords

  f32x4 acc[2][4];
  #pragma unroll
  for (int rt = 0; rt < 2; ++rt)
    #pragma unroll
    for (int ct = 0; ct < 4; ++ct) {
      f32x4 z = {0.f, 0.f, 0.f, 0.f};
      acc[rt][ct] = z;
    }

  for (int k0 = 0; k0 < K; k0 += 32) {
    // ---- stage A tile: 32 rows x 32 k ----
    if (a_is_f32) {
      float4 v = make_float4(0.f, 0.f, 0.f, 0.f);
      if (bm + row_s < M)
        v = *reinterpret_cast<const float4*>(Af + (size_t)(bm + row_s) * K + k0 + seg * 4);
      ushort4 u;
      u.x = f2bf(v.x); u.y = f2bf(v.y); u.z = f2bf(v.z); u.w = f2bf(v.w);
      *reinterpret_cast<ushort4*>(&As[row_s * 40 + seg * 4]) = u;
    } else {
      ushort4 u = make_ushort4(0, 0, 0, 0);
      if (bm + row_s < M)
        u = *reinterpret_cast<const ushort4*>(Ab + (size_t)(bm + row_s) * K + k0 + seg * 4);
      *reinterpret_cast<ushort4*>(&As[row_s * 40 + seg * 4]) = u;
    }
    // ---- stage B tile: 256 cols x 32 k (thread = col, 64B) ----
    {
      const uint4* srcq = reinterpret_cast<const uint4*>(Wt + (size_t)tid * K + k0);
      uint4 q0 = srcq[0], q1 = srcq[1], q2 = srcq[2], q3 = srcq[3];
      uint4* dstq = reinterpret_cast<uint4*>(&Bs[tid * 40]);
      dstq[0] = q0; dstq[1] = q1; dstq[2] = q2; dstq[3] = q3;
    }
    __syncthreads();
    // ---- fragments + MFMA ----
    short8 bf[4];
    #pragma unroll
    for (int ct = 0; ct < 4; ++ct)
      bf[ct] = *reinterpret_cast<const short8*>(&Bs[(w * 64 + ct * 16 + lr) * 40 + lk * 8]);
    #pragma unroll
    for (int rt = 0; rt < 2; ++rt) {
      short8 af = *reinterpret_cast<const short8*>(&As[(rt * 16 + lr) * 40 + lk * 8]);
      #pragma unroll
      for (int ct = 0; ct < 4; ++ct)
        acc[rt][ct] = __builtin_amdgcn_mfma_f32_16x16x32_bf16(af, bf[ct], acc[rt][ct], 0, 0, 0);
    }
    __syncthreads();
  }

  // ---- epilogue: channel-major bf16 tile in LDS ----
  #pragma unroll
  for (int rt = 0; rt < 2; ++rt)
    #pragma unroll
    for (int ct = 0; ct < 4; ++ct)
      #pragma unroll
      for (int r = 0; r < 4; ++r) {
        int row = rt * 16 + lk * 4 + r;
        int c = ct * 16 + lr;                 // channel within head
        Cs[row * 258 + c * 4 + w] = f2bf(acc[rt][ct][r]);
      }
  __syncthreads();

  // coalesced hb16 write: thread t copies 64B of one row
  if (bm + row_s < M) {
    ushort4* dst = reinterpret_cast<ushort4*>(hb16 + (size_t)(bm + row_s) * HC + seg * 32);
    const unsigned short* srcp = &Cs[row_s * 258 + seg * 32];
    #pragma unroll
    for (int q = 0; q < 4; ++q)
      dst[q] = *reinterpret_cast<const ushort4*>(srcp + q * 4);
  }

  // attention dots: 8 threads per node -> (head, half)
  {
    int nd = tid >> 3, q = tid & 7, h = q >> 1, half = q & 1;
    float ps = 0.f, pd = 0.f;
    const float* ats = att_s + h * 64 + half * 32;
    const float* atd = att_d + h * 64 + half * 32;
    const unsigned short* cp = &Cs[nd * 258 + (half * 32) * 4 + h];
    #pragma unroll
    for (int c = 0; c < 32; ++c) {
      float hv = bf2f(cp[c * 4]);
      ps += hv * ats[c];
      pd += hv * atd[c];
    }
    ps += __shfl_xor(ps, 1);
    pd += __shfl_xor(pd, 1);
    if (!(q & 1) && bm + nd < M) {
      a_src[(size_t)(bm + nd) * 4 + h] = ps;
      a_dst[(size_t)(bm + nd) * 4 + h] = pd;
    }
  }
}

// ================= CSR build (once per call) =================
__global__ __launch_bounds__(256) void zero2_k(int* __restrict__ a, int* __restrict__ b, int n) {
  int i = blockIdx.x * blockDim.x + threadIdx.x;
  if (i < n) { a[i] = 0; b[i] = 0; }
}

__global__ __launch_bounds__(256) void hist_k(const int* __restrict__ dst, int* __restrict__ count, int E) {
  int e = blockIdx.x * blockDim.x + threadIdx.x;
  if (e < E) atomicAdd(&count[dst[e]], 1);
}

__global__ __launch_bounds__(512) void scan1_k(const int* __restrict__ count,
                                               int* __restrict__ rp,
                                               int* __restrict__ bsum, int n) {
  __shared__ int sh[512];
  int tx = threadIdx.x;
  int i = blockIdx.x * 512 + tx;
  int v = (i < n) ? count[i] : 0;
  sh[tx] = v;
  __syncthreads();
  #pragma unroll
  for (int off = 1; off < 512; off <<= 1) {
    int t = (tx >= off) ? sh[tx - off] : 0;
    __syncthreads();
    sh[tx] += t;
    __syncthreads();
  }
  if (i < n) rp[i] = sh[tx] - v;          // exclusive
  if (tx == 511) bsum[blockIdx.x] = sh[511];
}

__global__ __launch_bounds__(128) void scan2_k(int* __restrict__ bsum, int nb) {
  __shared__ int sh[128];
  int tx = threadIdx.x;
  int v = (tx < nb) ? bsum[tx] : 0;
  sh[tx] = v;
  __syncthreads();
  #pragma unroll
  for (int off = 1; off < 128; off <<= 1) {
    int t = (tx >= off) ? sh[tx - off] : 0;
    __syncthreads();
    sh[tx] += t;
    __syncthreads();
  }
  if (tx < nb) bsum[tx] = sh[tx] - v;      // exclusive
}

__global__ __launch_bounds__(512) void scan3_k(int* __restrict__ rp, const int* __restrict__ bsum,
                                               int n, int E) {
  int i = blockIdx.x * 512 + threadIdx.x;
  if (i < n) rp[i] += bsum[blockIdx.x];
  if (i == 0) rp[n] = E;
}

__global__ __launch_bounds__(256) void scatter_k(const int* __restrict__ src, const int* __restrict__ dst,
                                                 const int* __restrict__ rp, int* __restrict__ cursor,
                                                 int* __restrict__ csr_src, int E) {
  int e = blockIdx.x * blockDim.x + threadIdx.x;
  if (e >= E) return;
  int d = dst[e];
  int pos = rp[d] + atomicAdd(&cursor[d], 1);
  csr_src[pos] = src[e];
}

// ------------- fused segment softmax over CSR -------------
__global__ __launch_bounds__(256) void att_soft_k(const int* __restrict__ rp,
                                                  const int* __restrict__ csr_src,
                                                  const float* __restrict__ a_src,
                                                  const float* __restrict__ a_dst,
                                                  float* __restrict__ pbuf,
                                                  float* __restrict__ rdn,
                                                  float* __restrict__ selfp,
                                                  int N) {
  int node = blockIdx.x * 16 + (threadIdx.x >> 4);
  int sub  = threadIdx.x & 15;
  if (node >= N) return;
  int rs = rp[node], re = rp[node + 1];
  float4 ad4 = *reinterpret_cast<const float4*>(a_dst + (size_t)node * 4);
  float4 asf = *reinterpret_cast<const float4*>(a_src + (size_t)node * 4);
  float es0 = lrelu(asf.x + ad4.x), es1 = lrelu(asf.y + ad4.y);
  float es2 = lrelu(asf.z + ad4.z), es3 = lrelu(asf.w + ad4.w);
  float m0 = es0, m1 = es1, m2 = es2, m3 = es3;
  for (int j = rs + sub; j < re; j += 16) {
    int s = csr_src[j];
    float4 as4 = *reinterpret_cast<const float4*>(a_src + (size_t)s * 4);
    float4 e4;
    e4.x = lrelu(as4.x + ad4.x); e4.y = lrelu(as4.y + ad4.y);
    e4.z = lrelu(as4.z + ad4.z); e4.w = lrelu(as4.w + ad4.w);
    *reinterpret_cast<float4*>(pbuf + (size_t)j * 4) = e4;
    m0 = fmaxf(m0, e4.x); m1 = fmaxf(m1, e4.y);
    m2 = fmaxf(m2, e4.z); m3 = fmaxf(m3, e4.w);
  }
  #pragma unroll
  for (int off = 8; off > 0; off >>= 1) {
    m0 = fmaxf(m0, __shfl_xor(m0, off, 16));
    m1 = fmaxf(m1, __shfl_xor(m1, off, 16));
    m2 = fmaxf(m2, __shfl_xor(m2, off, 16));
    m3 = fmaxf(m3, __shfl_xor(m3, off, 16));
  }
  float d0 = 0.f, d1 = 0.f, d2 = 0.f, d3 = 0.f;
  for (int j = rs + sub; j < re; j += 16) {
    float4 e4 = *reinterpret_cast<const float4*>(pbuf + (size_t)j * 4);
    float4 pv;
    pv.x = expf(e4.x - m0); pv.y = expf(e4.y - m1);
    pv.z = expf(e4.z - m2); pv.w = expf(e4.w - m3);
    *reinterpret_cast<float4*>(pbuf + (size_t)j * 4) = pv;
    d0 += pv.x; d1 += pv.y; d2 += pv.z; d3 += pv.w;
  }
  #pragma unroll
  for (int off = 8; off > 0; off >>= 1) {
    d0 += __shfl_xor(d0, off, 16);
    d1 += __shfl_xor(d1, off, 16);
    d2 += __shfl_xor(d2, off, 16);
    d3 += __shfl_xor(d3, off, 16);
  }
  float sp0 = expf(es0 - m0), sp1 = expf(es1 - m1);
  float sp2 = expf(es2 - m2), sp3 = expf(es3 - m3);
  d0 += sp0; d1 += sp1; d2 += sp2; d3 += sp3;
  if (sub == 0) {
    float4 r4 = make_float4(1.f / (d0 + EPSV), 1.f / (d1 + EPSV),
                            1.f / (d2 + EPSV), 1.f / (d3 + EPSV));
    float4 s4 = make_float4(sp0, sp1, sp2, sp3);
    *reinterpret_cast<float4*>(rdn   + (size_t)node * 4) = r4;
    *reinterpret_cast<float4*>(selfp + (size_t)node * 4) = s4;
  }
}

// ------------- gather-aggregate + finalize (wave per node, lane = channel) -------------
__global__ __launch_bounds__(256) void agg_fin_k(const int* __restrict__ rp,
                                                 const int* __restrict__ csr_src,
                                                 const float* __restrict__ pbuf,
                                                 const float* __restrict__ rdn,
                                                 const float* __restrict__ selfp,
                                                 const unsigned short* __restrict__ hb16,
                                                 const float* __restrict__ bias,
                                                 float* __restrict__ outf,
                                                 unsigned short* __restrict__ outb,
                                                 int N, int do_lsm) {
  int wid  = (blockIdx.x * blockDim.x + threadIdx.x) >> 6;
  int lane = threadIdx.x & 63;
  if (wid >= N) return;
  int rs = rp[wid], re = rp[wid + 1];
  float4 r4 = *reinterpret_cast<const float4*>(rdn   + (size_t)wid * 4);
  float4 sp = *reinterpret_cast<const float4*>(selfp + (size_t)wid * 4);
  float a0 = 0.f, a1 = 0.f, a2 = 0.f, a3 = 0.f;
  int j = rs;
  for (; j + 4 <= re; j += 4) {
    int s0 = csr_src[j + 0], s1 = csr_src[j + 1];
    int s2 = csr_src[j + 2], s3 = csr_src[j + 3];
    float4 p0 = *reinterpret_cast<const float4*>(pbuf + (size_t)(j + 0) * 4);
    float4 p1 = *reinterpret_cast<const float4*>(pbuf + (size_t)(j + 1) * 4);
    float4 p2 = *reinterpret_cast<const float4*>(pbuf + (size_t)(j + 2) * 4);
    float4 p3 = *reinterpret_cast<const float4*>(pbuf + (size_t)(j + 3) * 4);
    ushort4 h0 = *reinterpret_cast<const ushort4*>(hb16 + (size_t)s0 * HC + lane * 4);
    ushort4 h1 = *reinterpret_cast<const ushort4*>(hb16 + (size_t)s1 * HC + lane * 4);
    ushort4 h2 = *reinterpret_cast<const ushort4*>(hb16 + (size_t)s2 * HC + lane * 4);
    ushort4 h3 = *reinterpret_cast<const ushort4*>(hb16 + (size_t)s3 * HC + lane * 4);
    a0 += p0.x * bf2f(h0.x) + p1.x * bf2f(h1.x) + p2.x * bf2f(h2.x) + p3.x * bf2f(h3.x);
    a1 += p0.y * bf2f(h0.y) + p1.y * bf2f(h1.y) + p2.y * bf2f(h2.y) + p3.y * bf2f(h3.y);
    a2 += p0.z * bf2f(h0.z) + p1.z * bf2f(h1.z) + p2.z * bf2f(h2.z) + p3.z * bf2f(h3.z);
    a3 += p0.w * bf2f(h0.w) + p1.w * bf2f(h1.w) + p2.w * bf2f(h2.w) + p3.w * bf2f(h3.w);
  }
  for (; j < re; ++j) {
    int s = csr_src[j];
    float4 p4 = *reinterpret_cast<const float4*>(pbuf + (size_t)j * 4);
    ushort4 hv = *reinterpret_cast<const ushort4*>(hb16 + (size_t)s * HC + lane * 4);
    a0 += p4.x * bf2f(hv.x); a1 += p4.y * bf2f(hv.y);
    a2 += p4.z * bf2f(hv.z); a3 += p4.w * bf2f(hv.w);
  }
  // self message (bf16 h, own row - coalesced)
  ushort4 sh = *reinterpret_cast<const ushort4*>(hb16 + (size_t)wid * HC + lane * 4);
  float sum = (a0 + sp.x * bf2f(sh.x)) * r4.x
            + (a1 + sp.y * bf2f(sh.y)) * r4.y
            + (a2 + sp.z * bf2f(sh.z)) * r4.z
            + (a3 + sp.w * bf2f(sh.w)) * r4.w;
  float v = sum * 0.25f + bias[lane];
  v = fmaxf(v, 0.f);
  if (do_lsm) {
    float mx = v;
    #pragma unroll
    for (int off = 32; off > 0; off >>= 1) mx = fmaxf(mx, __shfl_xor(mx, off));
    float ex = expf(v - mx);
    float sm = ex;
    #pragma unroll
    for (int off = 32; off > 0; off >>= 1) sm += __shfl_xor(sm, off);
    outf[(size_t)wid * CH + lane] = v - mx - logf(sm);
  } else {
    outb[(size_t)wid * CH + lane] = f2bf(v);
  }
}

extern "C" void kernel_launch(void* const* d_in, const int* in_sizes, int n_in,
                              void* d_out, int out_size, void* d_ws, size_t ws_size,
                              hipStream_t stream) {
  const float* x0 = (const float*)d_in[0];
  const int*   ei = (const int*)d_in[1];
  int N = in_sizes[0] / HC;   // 50000
  int E = in_sizes[1] / 2;    // 800000
  const int* srcp = ei;
  const int* dstp = ei + E;

  const float* W[3]  = {(const float*)d_in[2], (const float*)d_in[6],  (const float*)d_in[10]};
  const float* AS[3] = {(const float*)d_in[3], (const float*)d_in[7],  (const float*)d_in[11]};
  const float* AD[3] = {(const float*)d_in[4], (const float*)d_in[8],  (const float*)d_in[12]};
  const float* BI[3] = {(const float*)d_in[5], (const float*)d_in[9],  (const float*)d_in[13]};
  int Kdim[3] = {256, 64, 64};

  char* ws = (char*)d_ws;
  size_t off = 0;
  auto alloc = [&](size_t bytes) {
    void* p = ws + off;
    off += (bytes + 255) & ~(size_t)255;
    return p;
  };
  unsigned short* hb16    = (unsigned short*)alloc((size_t)N * HC * 2); // 25.6 MB
  unsigned short* xb16    = (unsigned short*)alloc((size_t)N * CH * 2); // 6.4 MB
  float*          pbuf    = (float*)alloc((size_t)E * 4 * 4);           // 12.8 MB
  float*          a_s     = (float*)alloc((size_t)N * 4 * 4);
  float*          a_d     = (float*)alloc((size_t)N * 4 * 4);
  float*          rdn     = (float*)alloc((size_t)N * 4 * 4);
  float*          selfp   = (float*)alloc((size_t)N * 4 * 4);
  int*            rowp    = (int*)alloc((size_t)(N + 1) * 4);
  int*            cursor  = (int*)alloc((size_t)N * 4);
  int*            csr_src = (int*)alloc((size_t)E * 4);                 // 3.2 MB
  int*            bsum    = (int*)alloc(512 * 4);
  unsigned short* Wt[3];
  Wt[0] = (unsigned short*)alloc((size_t)256 * 256 * 2);
  Wt[1] = (unsigned short*)alloc((size_t)256 * 64 * 2);
  Wt[2] = (unsigned short*)alloc((size_t)256 * 64 * 2);

  // ---- weight prep (bf16 transposed) ----
  for (int L = 0; L < 3; ++L) {
    int tot = Kdim[L] * 256;
    wprep_k<<<(tot + 255) / 256, 256, 0, stream>>>(W[L], Wt[L], Kdim[L]);
  }

  // ---- build CSR by destination (once; reused by all 3 layers) ----
  int nb = (N + 511) / 512;
  zero2_k<<<(N + 255) / 256, 256, 0, stream>>>(cursor, rowp, N);
  hist_k<<<(E + 255) / 256, 256, 0, stream>>>(dstp, rowp, E);
  scan1_k<<<nb, 512, 0, stream>>>(rowp, rowp, bsum, N);
  scan2_k<<<1, 128, 0, stream>>>(bsum, nb);
  scan3_k<<<nb, 512, 0, stream>>>(rowp, bsum, N, E);
  scatter_k<<<(E + 255) / 256, 256, 0, stream>>>(srcp, dstp, rowp, cursor, csr_src, E);

  for (int L = 0; L < 3; ++L) {
    int K = Kdim[L];
    mfma_gat_k<<<(N + 31) / 32, 256, 0, stream>>>(
        (L == 0) ? x0 : nullptr, (L == 0) ? nullptr : xb16,
        Wt[L], AS[L], AD[L], hb16, a_s, a_d, N, K, (L == 0) ? 1 : 0);
    att_soft_k<<<(N + 15) / 16, 256, 0, stream>>>(rowp, csr_src, a_s, a_d, pbuf, rdn, selfp, N);
    agg_fin_k<<<(N + 3) / 4, 256, 0, stream>>>(rowp, csr_src, pbuf, rdn, selfp, hb16, BI[L],
                                               (float*)d_out, xb16, N, (L == 2) ? 1 : 0);
  }
}

// Round 6
// 421.393 us; speedup vs baseline: 4.3265x; 1.0586x over previous
//
#include <hip/hip_runtime.h>
#include <hip/hip_bf16.h>
#include <math.h>
#include <stdint.h>

#define HEADS 4
#define CH 64          // channels per head
#define HC 256         // HEADS*CH
#define NEG 0.2f
#define EPSV 1e-16f
#define NEGBIG -3.0e38f

typedef __attribute__((ext_vector_type(8))) short short8;
typedef __attribute__((ext_vector_type(4))) float f32x4;

__device__ __forceinline__ float lrelu(float x) { return x > 0.f ? x : NEG * x; }

__device__ __forceinline__ unsigned short f2bf(float f) {
  __hip_bfloat16 b = __float2bfloat16(f);   // RNE
  return *reinterpret_cast<unsigned short*>(&b);
}
__device__ __forceinline__ float bf2f(unsigned short u) {
  return __uint_as_float((unsigned)u << 16);
}

// ---------------- weight prep: Wt[n][k] bf16 from W[k][n] f32 ----------------
__global__ __launch_bounds__(256) void wprep_k(const float* __restrict__ W,
                                               unsigned short* __restrict__ Wt,
                                               int K) {
  int i = blockIdx.x * 256 + threadIdx.x;
  if (i >= K * 256) return;
  int k = i >> 8, n = i & 255;
  Wt[(size_t)n * K + k] = f2bf(W[i]);
}

// ---------------- fused MFMA GEMM + attention-dot epilogue ----------------
__global__ __launch_bounds__(256) void mfma_gat_k(const float* __restrict__ Af,
                                                  const unsigned short* __restrict__ Ab,
                                                  const unsigned short* __restrict__ Wt,
                                                  const float* __restrict__ att_s,
                                                  const float* __restrict__ att_d,
                                                  unsigned short* __restrict__ hb16,
                                                  float* __restrict__ a_src,
                                                  float* __restrict__ a_dst,
                                                  int M, int K, int a_is_f32) {
  __shared__ unsigned short As[32 * 40];    // [row][k] stride 40 (pad)
  __shared__ unsigned short Bs[256 * 40];   // [col][k] stride 40
  __shared__ unsigned short Cs[32 * 258];   // [row][chan*4+head] channel-major

  int tid = threadIdx.x;
  int bm = blockIdx.x * 32;
  int w = tid >> 6, l = tid & 63;
  int lr = l & 15, lk = l >> 4;
  int row_s = tid >> 3, seg = tid & 7;

  f32x4 acc[2][4];
  #pragma unroll
  for (int rt = 0; rt < 2; ++rt)
    #pragma unroll
    for (int ct = 0; ct < 4; ++ct) {
      f32x4 z = {0.f, 0.f, 0.f, 0.f};
      acc[rt][ct] = z;
    }

  for (int k0 = 0; k0 < K; k0 += 32) {
    if (a_is_f32) {
      float4 v = make_float4(0.f, 0.f, 0.f, 0.f);
      if (bm + row_s < M)
        v = *reinterpret_cast<const float4*>(Af + (size_t)(bm + row_s) * K + k0 + seg * 4);
      ushort4 u;
      u.x = f2bf(v.x); u.y = f2bf(v.y); u.z = f2bf(v.z); u.w = f2bf(v.w);
      *reinterpret_cast<ushort4*>(&As[row_s * 40 + seg * 4]) = u;
    } else {
      ushort4 u = make_ushort4(0, 0, 0, 0);
      if (bm + row_s < M)
        u = *reinterpret_cast<const ushort4*>(Ab + (size_t)(bm + row_s) * K + k0 + seg * 4);
      *reinterpret_cast<ushort4*>(&As[row_s * 40 + seg * 4]) = u;
    }
    {
      const uint4* srcq = reinterpret_cast<const uint4*>(Wt + (size_t)tid * K + k0);
      uint4 q0 = srcq[0], q1 = srcq[1], q2 = srcq[2], q3 = srcq[3];
      uint4* dstq = reinterpret_cast<uint4*>(&Bs[tid * 40]);
      dstq[0] = q0; dstq[1] = q1; dstq[2] = q2; dstq[3] = q3;
    }
    __syncthreads();
    short8 bfr[4];
    #pragma unroll
    for (int ct = 0; ct < 4; ++ct)
      bfr[ct] = *reinterpret_cast<const short8*>(&Bs[(w * 64 + ct * 16 + lr) * 40 + lk * 8]);
    #pragma unroll
    for (int rt = 0; rt < 2; ++rt) {
      short8 af = *reinterpret_cast<const short8*>(&As[(rt * 16 + lr) * 40 + lk * 8]);
      #pragma unroll
      for (int ct = 0; ct < 4; ++ct)
        acc[rt][ct] = __builtin_amdgcn_mfma_f32_16x16x32_bf16(af, bfr[ct], acc[rt][ct], 0, 0, 0);
    }
    __syncthreads();
  }

  #pragma unroll
  for (int rt = 0; rt < 2; ++rt)
    #pragma unroll
    for (int ct = 0; ct < 4; ++ct)
      #pragma unroll
      for (int r = 0; r < 4; ++r) {
        int row = rt * 16 + lk * 4 + r;
        int c = ct * 16 + lr;
        Cs[row * 258 + c * 4 + w] = f2bf(acc[rt][ct][r]);
      }
  __syncthreads();

  if (bm + row_s < M) {
    ushort4* dst = reinterpret_cast<ushort4*>(hb16 + (size_t)(bm + row_s) * HC + seg * 32);
    const unsigned short* srcp = &Cs[row_s * 258 + seg * 32];
    #pragma unroll
    for (int q = 0; q < 4; ++q)
      dst[q] = *reinterpret_cast<const ushort4*>(srcp + q * 4);
  }

  {
    int nd = tid >> 3, q = tid & 7, h = q >> 1, half = q & 1;
    float ps = 0.f, pd = 0.f;
    const float* ats = att_s + h * 64 + half * 32;
    const float* atd = att_d + h * 64 + half * 32;
    const unsigned short* cp = &Cs[nd * 258 + (half * 32) * 4 + h];
    #pragma unroll
    for (int c = 0; c < 32; ++c) {
      float hv = bf2f(cp[c * 4]);
      ps += hv * ats[c];
      pd += hv * atd[c];
    }
    ps += __shfl_xor(ps, 1);
    pd += __shfl_xor(pd, 1);
    if (!(q & 1) && bm + nd < M) {
      a_src[(size_t)(bm + nd) * 4 + h] = ps;
      a_dst[(size_t)(bm + nd) * 4 + h] = pd;
    }
  }
}

// ================= CSR build (once per call) =================
__global__ __launch_bounds__(256) void zero2_k(int* __restrict__ a, int* __restrict__ b, int n) {
  int i = blockIdx.x * blockDim.x + threadIdx.x;
  if (i < n) { a[i] = 0; b[i] = 0; }
}

__global__ __launch_bounds__(256) void hist_k(const int* __restrict__ dst, int* __restrict__ count, int E) {
  int e = blockIdx.x * blockDim.x + threadIdx.x;
  if (e < E) atomicAdd(&count[dst[e]], 1);
}

__global__ __launch_bounds__(512) void scan1_k(const int* __restrict__ count,
                                               int* __restrict__ rp,
                                               int* __restrict__ bsum, int n) {
  __shared__ int sh[512];
  int tx = threadIdx.x;
  int i = blockIdx.x * 512 + tx;
  int v = (i < n) ? count[i] : 0;
  sh[tx] = v;
  __syncthreads();
  #pragma unroll
  for (int off = 1; off < 512; off <<= 1) {
    int t = (tx >= off) ? sh[tx - off] : 0;
    __syncthreads();
    sh[tx] += t;
    __syncthreads();
  }
  if (i < n) rp[i] = sh[tx] - v;          // exclusive
  if (tx == 511) bsum[blockIdx.x] = sh[511];
}

__global__ __launch_bounds__(128) void scan2_k(int* __restrict__ bsum, int nb) {
  __shared__ int sh[128];
  int tx = threadIdx.x;
  int v = (tx < nb) ? bsum[tx] : 0;
  sh[tx] = v;
  __syncthreads();
  #pragma unroll
  for (int off = 1; off < 128; off <<= 1) {
    int t = (tx >= off) ? sh[tx - off] : 0;
    __syncthreads();
    sh[tx] += t;
    __syncthreads();
  }
  if (tx < nb) bsum[tx] = sh[tx] - v;      // exclusive
}

__global__ __launch_bounds__(512) void scan3_k(int* __restrict__ rp, const int* __restrict__ bsum,
                                               int n, int E) {
  int i = blockIdx.x * 512 + threadIdx.x;
  if (i < n) rp[i] += bsum[blockIdx.x];
  if (i == 0) rp[n] = E;
}

__global__ __launch_bounds__(256) void scatter_k(const int* __restrict__ src, const int* __restrict__ dst,
                                                 const int* __restrict__ rp, int* __restrict__ cursor,
                                                 int* __restrict__ csr_src, int E) {
  int e = blockIdx.x * blockDim.x + threadIdx.x;
  if (e >= E) return;
  int d = dst[e];
  int pos = rp[d] + atomicAdd(&cursor[d], 1);
  csr_src[pos] = src[e];
}

// ------------- FUSED segment softmax + gather-aggregate + finalize -------------
// One wave per node. Phase A: lane=edge, compute e, wave-reduce max.
// Phase B/C per 64-edge chunk: lane computes its edge's p=exp(e-m); aggregation
// loop broadcasts (s,p4) from owner lane via __shfl while lane=channel
// accumulates Sum p*h. Normalization (1/denom) applied once at the end.
__global__ __launch_bounds__(256) void soft_agg_k(const int* __restrict__ rp,
                                                  const int* __restrict__ csr_src,
                                                  const float* __restrict__ a_src,
                                                  const float* __restrict__ a_dst,
                                                  const unsigned short* __restrict__ hb16,
                                                  const float* __restrict__ bias,
                                                  float* __restrict__ outf,
                                                  unsigned short* __restrict__ outb,
                                                  int N, int do_lsm) {
  int wid  = (blockIdx.x * blockDim.x + threadIdx.x) >> 6;
  int lane = threadIdx.x & 63;
  if (wid >= N) return;
  int rs = rp[wid], re = rp[wid + 1];

  float4 ad4 = *reinterpret_cast<const float4*>(a_dst + (size_t)wid * 4);
  float4 asn = *reinterpret_cast<const float4*>(a_src + (size_t)wid * 4);
  float es0 = lrelu(asn.x + ad4.x), es1 = lrelu(asn.y + ad4.y);
  float es2 = lrelu(asn.z + ad4.z), es3 = lrelu(asn.w + ad4.w);

  // ---- phase A: per-lane e for chunk 0 (registers), max over all edges ----
  int sreg = 0;
  float e0 = NEGBIG, e1 = NEGBIG, e2 = NEGBIG, e3 = NEGBIG;
  if (rs + lane < re) {
    sreg = csr_src[rs + lane];
    float4 a = *reinterpret_cast<const float4*>(a_src + (size_t)sreg * 4);
    e0 = lrelu(a.x + ad4.x); e1 = lrelu(a.y + ad4.y);
    e2 = lrelu(a.z + ad4.z); e3 = lrelu(a.w + ad4.w);
  }
  float m0 = fmaxf(es0, e0), m1 = fmaxf(es1, e1);
  float m2 = fmaxf(es2, e2), m3 = fmaxf(es3, e3);
  for (int base = rs + 64; base < re; base += 64) {   // rare (deg > 64)
    if (base + lane < re) {
      int s = csr_src[base + lane];
      float4 a = *reinterpret_cast<const float4*>(a_src + (size_t)s * 4);
      m0 = fmaxf(m0, lrelu(a.x + ad4.x)); m1 = fmaxf(m1, lrelu(a.y + ad4.y));
      m2 = fmaxf(m2, lrelu(a.z + ad4.z)); m3 = fmaxf(m3, lrelu(a.w + ad4.w));
    }
  }
  #pragma unroll
  for (int off = 32; off > 0; off >>= 1) {
    m0 = fmaxf(m0, __shfl_xor(m0, off));
    m1 = fmaxf(m1, __shfl_xor(m1, off));
    m2 = fmaxf(m2, __shfl_xor(m2, off));
    m3 = fmaxf(m3, __shfl_xor(m3, off));
  }

  // ---- phase B/C: p = exp(e-m), aggregate via shfl broadcast ----
  float a0 = 0.f, a1 = 0.f, a2 = 0.f, a3 = 0.f;   // channel accumulators
  float dn0 = 0.f, dn1 = 0.f, dn2 = 0.f, dn3 = 0.f; // per-lane denom partials

  auto agg_chunk = [&](int sv, float px, float py, float pz, float pw, int cnt) {
    int k = 0;
    for (; k + 4 <= cnt; k += 4) {
      int t0 = __shfl(sv, k + 0), t1 = __shfl(sv, k + 1);
      int t2 = __shfl(sv, k + 2), t3 = __shfl(sv, k + 3);
      ushort4 h0 = *reinterpret_cast<const ushort4*>(hb16 + (size_t)t0 * HC + lane * 4);
      ushort4 h1 = *reinterpret_cast<const ushort4*>(hb16 + (size_t)t1 * HC + lane * 4);
      ushort4 h2 = *reinterpret_cast<const ushort4*>(hb16 + (size_t)t2 * HC + lane * 4);
      ushort4 h3 = *reinterpret_cast<const ushort4*>(hb16 + (size_t)t3 * HC + lane * 4);
      float q0x = __shfl(px, k + 0), q1x = __shfl(px, k + 1), q2x = __shfl(px, k + 2), q3x = __shfl(px, k + 3);
      float q0y = __shfl(py, k + 0), q1y = __shfl(py, k + 1), q2y = __shfl(py, k + 2), q3y = __shfl(py, k + 3);
      float q0z = __shfl(pz, k + 0), q1z = __shfl(pz, k + 1), q2z = __shfl(pz, k + 2), q3z = __shfl(pz, k + 3);
      float q0w = __shfl(pw, k + 0), q1w = __shfl(pw, k + 1), q2w = __shfl(pw, k + 2), q3w = __shfl(pw, k + 3);
      a0 += q0x * bf2f(h0.x) + q1x * bf2f(h1.x) + q2x * bf2f(h2.x) + q3x * bf2f(h3.x);
      a1 += q0y * bf2f(h0.y) + q1y * bf2f(h1.y) + q2y * bf2f(h2.y) + q3y * bf2f(h3.y);
      a2 += q0z * bf2f(h0.z) + q1z * bf2f(h1.z) + q2z * bf2f(h2.z) + q3z * bf2f(h3.z);
      a3 += q0w * bf2f(h0.w) + q1w * bf2f(h1.w) + q2w * bf2f(h2.w) + q3w * bf2f(h3.w);
    }
    for (; k < cnt; ++k) {
      int t = __shfl(sv, k);
      ushort4 hv = *reinterpret_cast<const ushort4*>(hb16 + (size_t)t * HC + lane * 4);
      float qx = __shfl(px, k), qy = __shfl(py, k), qz = __shfl(pz, k), qw = __shfl(pw, k);
      a0 += qx * bf2f(hv.x); a1 += qy * bf2f(hv.y);
      a2 += qz * bf2f(hv.z); a3 += qw * bf2f(hv.w);
    }
  };

  // chunk 0 (register path)
  {
    float px = expf(e0 - m0), py = expf(e1 - m1);
    float pz = expf(e2 - m2), pw = expf(e3 - m3);
    dn0 += px; dn1 += py; dn2 += pz; dn3 += pw;
    int cnt = re - rs; if (cnt > 64) cnt = 64;
    agg_chunk(sreg, px, py, pz, pw, cnt);
  }
  // extra chunks (deg > 64, rare): recompute e
  for (int base = rs + 64; base < re; base += 64) {
    int s = 0;
    float f0 = NEGBIG, f1 = NEGBIG, f2 = NEGBIG, f3 = NEGBIG;
    if (base + lane < re) {
      s = csr_src[base + lane];
      float4 a = *reinterpret_cast<const float4*>(a_src + (size_t)s * 4);
      f0 = lrelu(a.x + ad4.x); f1 = lrelu(a.y + ad4.y);
      f2 = lrelu(a.z + ad4.z); f3 = lrelu(a.w + ad4.w);
    }
    float px = expf(f0 - m0), py = expf(f1 - m1);
    float pz = expf(f2 - m2), pw = expf(f3 - m3);
    dn0 += px; dn1 += py; dn2 += pz; dn3 += pw;
    int cnt = re - base; if (cnt > 64) cnt = 64;
    agg_chunk(s, px, py, pz, pw, cnt);
  }

  // ---- reduce denom across lanes, add self, invert ----
  #pragma unroll
  for (int off = 32; off > 0; off >>= 1) {
    dn0 += __shfl_xor(dn0, off);
    dn1 += __shfl_xor(dn1, off);
    dn2 += __shfl_xor(dn2, off);
    dn3 += __shfl_xor(dn3, off);
  }
  float sp0 = expf(es0 - m0), sp1 = expf(es1 - m1);
  float sp2 = expf(es2 - m2), sp3 = expf(es3 - m3);
  dn0 += sp0; dn1 += sp1; dn2 += sp2; dn3 += sp3;
  float r0 = 1.f / (dn0 + EPSV), r1 = 1.f / (dn1 + EPSV);
  float r2 = 1.f / (dn2 + EPSV), r3 = 1.f / (dn3 + EPSV);

  // ---- self message + finalize ----
  ushort4 sh = *reinterpret_cast<const ushort4*>(hb16 + (size_t)wid * HC + lane * 4);
  float sum = (a0 + sp0 * bf2f(sh.x)) * r0
            + (a1 + sp1 * bf2f(sh.y)) * r1
            + (a2 + sp2 * bf2f(sh.z)) * r2
            + (a3 + sp3 * bf2f(sh.w)) * r3;
  float v = sum * 0.25f + bias[lane];
  v = fmaxf(v, 0.f);
  if (do_lsm) {
    float mx = v;
    #pragma unroll
    for (int off = 32; off > 0; off >>= 1) mx = fmaxf(mx, __shfl_xor(mx, off));
    float ex = expf(v - mx);
    float sm = ex;
    #pragma unroll
    for (int off = 32; off > 0; off >>= 1) sm += __shfl_xor(sm, off);
    outf[(size_t)wid * CH + lane] = v - mx - logf(sm);
  } else {
    outb[(size_t)wid * CH + lane] = f2bf(v);
  }
}

extern "C" void kernel_launch(void* const* d_in, const int* in_sizes, int n_in,
                              void* d_out, int out_size, void* d_ws, size_t ws_size,
                              hipStream_t stream) {
  const float* x0 = (const float*)d_in[0];
  const int*   ei = (const int*)d_in[1];
  int N = in_sizes[0] / HC;   // 50000
  int E = in_sizes[1] / 2;    // 800000
  const int* srcp = ei;
  const int* dstp = ei + E;

  const float* W[3]  = {(const float*)d_in[2], (const float*)d_in[6],  (const float*)d_in[10]};
  const float* AS[3] = {(const float*)d_in[3], (const float*)d_in[7],  (const float*)d_in[11]};
  const float* AD[3] = {(const float*)d_in[4], (const float*)d_in[8],  (const float*)d_in[12]};
  const float* BI[3] = {(const float*)d_in[5], (const float*)d_in[9],  (const float*)d_in[13]};
  int Kdim[3] = {256, 64, 64};

  char* ws = (char*)d_ws;
  size_t off = 0;
  auto alloc = [&](size_t bytes) {
    void* p = ws + off;
    off += (bytes + 255) & ~(size_t)255;
    return p;
  };
  unsigned short* hb16    = (unsigned short*)alloc((size_t)N * HC * 2); // 25.6 MB
  unsigned short* xb16    = (unsigned short*)alloc((size_t)N * CH * 2); // 6.4 MB
  float*          a_s     = (float*)alloc((size_t)N * 4 * 4);
  float*          a_d     = (float*)alloc((size_t)N * 4 * 4);
  int*            rowp    = (int*)alloc((size_t)(N + 1) * 4);
  int*            cursor  = (int*)alloc((size_t)N * 4);
  int*            csr_src = (int*)alloc((size_t)E * 4);                 // 3.2 MB
  int*            bsum    = (int*)alloc(512 * 4);
  unsigned short* Wt[3];
  Wt[0] = (unsigned short*)alloc((size_t)256 * 256 * 2);
  Wt[1] = (unsigned short*)alloc((size_t)256 * 64 * 2);
  Wt[2] = (unsigned short*)alloc((size_t)256 * 64 * 2);

  // ---- weight prep (bf16 transposed) ----
  for (int L = 0; L < 3; ++L) {
    int tot = Kdim[L] * 256;
    wprep_k<<<(tot + 255) / 256, 256, 0, stream>>>(W[L], Wt[L], Kdim[L]);
  }

  // ---- build CSR by destination (once; reused by all 3 layers) ----
  int nb = (N + 511) / 512;
  zero2_k<<<(N + 255) / 256, 256, 0, stream>>>(cursor, rowp, N);
  hist_k<<<(E + 255) / 256, 256, 0, stream>>>(dstp, rowp, E);
  scan1_k<<<nb, 512, 0, stream>>>(rowp, rowp, bsum, N);
  scan2_k<<<1, 128, 0, stream>>>(bsum, nb);
  scan3_k<<<nb, 512, 0, stream>>>(rowp, bsum, N, E);
  scatter_k<<<(E + 255) / 256, 256, 0, stream>>>(srcp, dstp, rowp, cursor, csr_src, E);

  for (int L = 0; L < 3; ++L) {
    int K = Kdim[L];
    mfma_gat_k<<<(N + 31) / 32, 256, 0, stream>>>(
        (L == 0) ? x0 : nullptr, (L == 0) ? nullptr : xb16,
        Wt[L], AS[L], AD[L], hb16, a_s, a_d, N, K, (L == 0) ? 1 : 0);
    soft_agg_k<<<(N + 3) / 4, 256, 0, stream>>>(rowp, csr_src, a_s, a_d, hb16, BI[L],
                                                (float*)d_out, xb16, N, (L == 2) ? 1 : 0);
  }
}

// Round 7
// 402.071 us; speedup vs baseline: 4.5344x; 1.0481x over previous
//
#include <hip/hip_runtime.h>
#include <hip/hip_bf16.h>
#include <math.h>
#include <stdint.h>

#define HEADS 4
#define CH 64          // channels per head
#define HC 256         // HEADS*CH
#define NEG 0.2f
#define EPSV 1e-16f
#define NEGBIG -3.0e38f

typedef __attribute__((ext_vector_type(8))) short short8;
typedef __attribute__((ext_vector_type(4))) float f32x4;

__device__ __forceinline__ float lrelu(float x) { return x > 0.f ? x : NEG * x; }

__device__ __forceinline__ unsigned short f2bf(float f) {
  __hip_bfloat16 b = __float2bfloat16(f);   // RNE
  return *reinterpret_cast<unsigned short*>(&b);
}
__device__ __forceinline__ float bf2f(unsigned short u) {
  return __uint_as_float((unsigned)u << 16);
}
__device__ __forceinline__ unsigned int packbf2(float a, float b) {
  return (unsigned int)f2bf(a) | ((unsigned int)f2bf(b) << 16);
}
__device__ __forceinline__ float unpack_lo(unsigned int v) {
  return __uint_as_float(v << 16);
}
__device__ __forceinline__ float unpack_hi(unsigned int v) {
  return __uint_as_float(v & 0xffff0000u);
}

// ---------------- weight prep: Wt[n][k] bf16 from W[k][n] f32 ----------------
__global__ __launch_bounds__(256) void wprep_k(const float* __restrict__ W,
                                               unsigned short* __restrict__ Wt,
                                               int K) {
  int i = blockIdx.x * 256 + threadIdx.x;
  if (i >= K * 256) return;
  int k = i >> 8, n = i & 255;
  Wt[(size_t)n * K + k] = f2bf(W[i]);
}

// ---------------- fused MFMA GEMM + attention-dot epilogue ----------------
__global__ __launch_bounds__(256) void mfma_gat_k(const float* __restrict__ Af,
                                                  const unsigned short* __restrict__ Ab,
                                                  const unsigned short* __restrict__ Wt,
                                                  const float* __restrict__ att_s,
                                                  const float* __restrict__ att_d,
                                                  unsigned short* __restrict__ hb16,
                                                  float* __restrict__ a_src,
                                                  float* __restrict__ a_dst,
                                                  int M, int K, int a_is_f32) {
  __shared__ unsigned short As[32 * 40];    // [row][k] stride 40 (pad)
  __shared__ unsigned short Bs[256 * 40];   // [col][k] stride 40
  __shared__ unsigned short Cs[32 * 258];   // [row][chan*4+head] channel-major

  int tid = threadIdx.x;
  int bm = blockIdx.x * 32;
  int w = tid >> 6, l = tid & 63;
  int lr = l & 15, lk = l >> 4;
  int row_s = tid >> 3, seg = tid & 7;

  f32x4 acc[2][4];
  #pragma unroll
  for (int rt = 0; rt < 2; ++rt)
    #pragma unroll
    for (int ct = 0; ct < 4; ++ct) {
      f32x4 z = {0.f, 0.f, 0.f, 0.f};
      acc[rt][ct] = z;
    }

  for (int k0 = 0; k0 < K; k0 += 32) {
    if (a_is_f32) {
      float4 v = make_float4(0.f, 0.f, 0.f, 0.f);
      if (bm + row_s < M)
        v = *reinterpret_cast<const float4*>(Af + (size_t)(bm + row_s) * K + k0 + seg * 4);
      ushort4 u;
      u.x = f2bf(v.x); u.y = f2bf(v.y); u.z = f2bf(v.z); u.w = f2bf(v.w);
      *reinterpret_cast<ushort4*>(&As[row_s * 40 + seg * 4]) = u;
    } else {
      ushort4 u = make_ushort4(0, 0, 0, 0);
      if (bm + row_s < M)
        u = *reinterpret_cast<const ushort4*>(Ab + (size_t)(bm + row_s) * K + k0 + seg * 4);
      *reinterpret_cast<ushort4*>(&As[row_s * 40 + seg * 4]) = u;
    }
    {
      const uint4* srcq = reinterpret_cast<const uint4*>(Wt + (size_t)tid * K + k0);
      uint4 q0 = srcq[0], q1 = srcq[1], q2 = srcq[2], q3 = srcq[3];
      uint4* dstq = reinterpret_cast<uint4*>(&Bs[tid * 40]);
      dstq[0] = q0; dstq[1] = q1; dstq[2] = q2; dstq[3] = q3;
    }
    __syncthreads();
    short8 bfr[4];
    #pragma unroll
    for (int ct = 0; ct < 4; ++ct)
      bfr[ct] = *reinterpret_cast<const short8*>(&Bs[(w * 64 + ct * 16 + lr) * 40 + lk * 8]);
    #pragma unroll
    for (int rt = 0; rt < 2; ++rt) {
      short8 af = *reinterpret_cast<const short8*>(&As[(rt * 16 + lr) * 40 + lk * 8]);
      #pragma unroll
      for (int ct = 0; ct < 4; ++ct)
        acc[rt][ct] = __builtin_amdgcn_mfma_f32_16x16x32_bf16(af, bfr[ct], acc[rt][ct], 0, 0, 0);
    }
    __syncthreads();
  }

  #pragma unroll
  for (int rt = 0; rt < 2; ++rt)
    #pragma unroll
    for (int ct = 0; ct < 4; ++ct)
      #pragma unroll
      for (int r = 0; r < 4; ++r) {
        int row = rt * 16 + lk * 4 + r;
        int c = ct * 16 + lr;
        Cs[row * 258 + c * 4 + w] = f2bf(acc[rt][ct][r]);
      }
  __syncthreads();

  if (bm + row_s < M) {
    ushort4* dst = reinterpret_cast<ushort4*>(hb16 + (size_t)(bm + row_s) * HC + seg * 32);
    const unsigned short* srcp = &Cs[row_s * 258 + seg * 32];
    #pragma unroll
    for (int q = 0; q < 4; ++q)
      dst[q] = *reinterpret_cast<const ushort4*>(srcp + q * 4);
  }

  {
    int nd = tid >> 3, q = tid & 7, h = q >> 1, half = q & 1;
    float ps = 0.f, pd = 0.f;
    const float* ats = att_s + h * 64 + half * 32;
    const float* atd = att_d + h * 64 + half * 32;
    const unsigned short* cp = &Cs[nd * 258 + (half * 32) * 4 + h];
    #pragma unroll
    for (int c = 0; c < 32; ++c) {
      float hv = bf2f(cp[c * 4]);
      ps += hv * ats[c];
      pd += hv * atd[c];
    }
    ps += __shfl_xor(ps, 1);
    pd += __shfl_xor(pd, 1);
    if (!(q & 1) && bm + nd < M) {
      a_src[(size_t)(bm + nd) * 4 + h] = ps;
      a_dst[(size_t)(bm + nd) * 4 + h] = pd;
    }
  }
}

// ================= CSR build (once per call) =================
__global__ __launch_bounds__(256) void zero2_k(int* __restrict__ a, int* __restrict__ b, int n) {
  int i = blockIdx.x * blockDim.x + threadIdx.x;
  if (i < n) { a[i] = 0; b[i] = 0; }
}

__global__ __launch_bounds__(256) void hist_k(const int* __restrict__ dst, int* __restrict__ count, int E) {
  int e = blockIdx.x * blockDim.x + threadIdx.x;
  if (e < E) atomicAdd(&count[dst[e]], 1);
}

__global__ __launch_bounds__(512) void scan1_k(const int* __restrict__ count,
                                               int* __restrict__ rp,
                                               int* __restrict__ bsum, int n) {
  __shared__ int sh[512];
  int tx = threadIdx.x;
  int i = blockIdx.x * 512 + tx;
  int v = (i < n) ? count[i] : 0;
  sh[tx] = v;
  __syncthreads();
  #pragma unroll
  for (int off = 1; off < 512; off <<= 1) {
    int t = (tx >= off) ? sh[tx - off] : 0;
    __syncthreads();
    sh[tx] += t;
    __syncthreads();
  }
  if (i < n) rp[i] = sh[tx] - v;          // exclusive
  if (tx == 511) bsum[blockIdx.x] = sh[511];
}

__global__ __launch_bounds__(128) void scan2_k(int* __restrict__ bsum, int nb) {
  __shared__ int sh[128];
  int tx = threadIdx.x;
  int v = (tx < nb) ? bsum[tx] : 0;
  sh[tx] = v;
  __syncthreads();
  #pragma unroll
  for (int off = 1; off < 128; off <<= 1) {
    int t = (tx >= off) ? sh[tx - off] : 0;
    __syncthreads();
    sh[tx] += t;
    __syncthreads();
  }
  if (tx < nb) bsum[tx] = sh[tx] - v;      // exclusive
}

__global__ __launch_bounds__(512) void scan3_k(int* __restrict__ rp, const int* __restrict__ bsum,
                                               int n, int E) {
  int i = blockIdx.x * 512 + threadIdx.x;
  if (i < n) rp[i] += bsum[blockIdx.x];
  if (i == 0) rp[n] = E;
}

__global__ __launch_bounds__(256) void scatter_k(const int* __restrict__ src, const int* __restrict__ dst,
                                                 const int* __restrict__ rp, int* __restrict__ cursor,
                                                 int* __restrict__ csr_src, int E) {
  int e = blockIdx.x * blockDim.x + threadIdx.x;
  if (e >= E) return;
  int d = dst[e];
  int pos = rp[d] + atomicAdd(&cursor[d], 1);
  csr_src[pos] = src[e];
}

// ------------- FUSED segment softmax + gather-aggregate + finalize -------------
// One wave per node. Per 64-edge chunk: lane computes its edge's p=exp(e-m),
// packs (s, bf16 p x4) into a 16B LDS record; aggregation loop reads record k
// at a wave-uniform address (one broadcast ds_read_b128 per edge) while
// lane=channel accumulates Sum p*h. Normalization applied once at the end.
__global__ __launch_bounds__(256) void soft_agg_k(const int* __restrict__ rp,
                                                  const int* __restrict__ csr_src,
                                                  const float* __restrict__ a_src,
                                                  const float* __restrict__ a_dst,
                                                  const unsigned short* __restrict__ hb16,
                                                  const float* __restrict__ bias,
                                                  float* __restrict__ outf,
                                                  unsigned short* __restrict__ outb,
                                                  int N, int do_lsm) {
  __shared__ uint4 rec[4][64];              // per-wave private 64 edge records
  int tid  = threadIdx.x;
  int w    = tid >> 6;
  int lane = tid & 63;
  int wid  = (blockIdx.x * blockDim.x + tid) >> 6;
  if (wid >= N) return;
  int rs = rp[wid], re = rp[wid + 1];

  float4 ad4 = *reinterpret_cast<const float4*>(a_dst + (size_t)wid * 4);
  float4 asn = *reinterpret_cast<const float4*>(a_src + (size_t)wid * 4);
  float es0 = lrelu(asn.x + ad4.x), es1 = lrelu(asn.y + ad4.y);
  float es2 = lrelu(asn.z + ad4.z), es3 = lrelu(asn.w + ad4.w);

  // ---- phase A: per-lane e for chunk 0 (registers), max over all edges ----
  int sreg = 0;
  float e0 = NEGBIG, e1 = NEGBIG, e2 = NEGBIG, e3 = NEGBIG;
  if (rs + lane < re) {
    sreg = csr_src[rs + lane];
    float4 a = *reinterpret_cast<const float4*>(a_src + (size_t)sreg * 4);
    e0 = lrelu(a.x + ad4.x); e1 = lrelu(a.y + ad4.y);
    e2 = lrelu(a.z + ad4.z); e3 = lrelu(a.w + ad4.w);
  }
  float m0 = fmaxf(es0, e0), m1 = fmaxf(es1, e1);
  float m2 = fmaxf(es2, e2), m3 = fmaxf(es3, e3);
  for (int base = rs + 64; base < re; base += 64) {   // rare (deg > 64)
    if (base + lane < re) {
      int s = csr_src[base + lane];
      float4 a = *reinterpret_cast<const float4*>(a_src + (size_t)s * 4);
      m0 = fmaxf(m0, lrelu(a.x + ad4.x)); m1 = fmaxf(m1, lrelu(a.y + ad4.y));
      m2 = fmaxf(m2, lrelu(a.z + ad4.z)); m3 = fmaxf(m3, lrelu(a.w + ad4.w));
    }
  }
  #pragma unroll
  for (int off = 32; off > 0; off >>= 1) {
    m0 = fmaxf(m0, __shfl_xor(m0, off));
    m1 = fmaxf(m1, __shfl_xor(m1, off));
    m2 = fmaxf(m2, __shfl_xor(m2, off));
    m3 = fmaxf(m3, __shfl_xor(m3, off));
  }

  // ---- phase B/C: p = exp(e-m) packed into LDS, aggregate via broadcast reads ----
  float a0 = 0.f, a1 = 0.f, a2 = 0.f, a3 = 0.f;     // channel accumulators
  float dn0 = 0.f, dn1 = 0.f, dn2 = 0.f, dn3 = 0.f; // per-lane denom partials
  uint4* recw = &rec[w][0];
  const unsigned short* hl = hb16 + lane * 4;

  auto agg_lds = [&](int cnt) {
    int k = 0;
    for (; k + 4 <= cnt; k += 4) {
      uint4 r0 = recw[k + 0], r1 = recw[k + 1], r2 = recw[k + 2], r3 = recw[k + 3];
      ushort4 h0 = *reinterpret_cast<const ushort4*>(hl + (size_t)r0.x * HC);
      ushort4 h1 = *reinterpret_cast<const ushort4*>(hl + (size_t)r1.x * HC);
      ushort4 h2 = *reinterpret_cast<const ushort4*>(hl + (size_t)r2.x * HC);
      ushort4 h3 = *reinterpret_cast<const ushort4*>(hl + (size_t)r3.x * HC);
      a0 += unpack_lo(r0.y) * bf2f(h0.x) + unpack_lo(r1.y) * bf2f(h1.x)
          + unpack_lo(r2.y) * bf2f(h2.x) + unpack_lo(r3.y) * bf2f(h3.x);
      a1 += unpack_hi(r0.y) * bf2f(h0.y) + unpack_hi(r1.y) * bf2f(h1.y)
          + unpack_hi(r2.y) * bf2f(h2.y) + unpack_hi(r3.y) * bf2f(h3.y);
      a2 += unpack_lo(r0.z) * bf2f(h0.z) + unpack_lo(r1.z) * bf2f(h1.z)
          + unpack_lo(r2.z) * bf2f(h2.z) + unpack_lo(r3.z) * bf2f(h3.z);
      a3 += unpack_hi(r0.z) * bf2f(h0.w) + unpack_hi(r1.z) * bf2f(h1.w)
          + unpack_hi(r2.z) * bf2f(h2.w) + unpack_hi(r3.z) * bf2f(h3.w);
    }
    for (; k < cnt; ++k) {
      uint4 r0 = recw[k];
      ushort4 hv = *reinterpret_cast<const ushort4*>(hl + (size_t)r0.x * HC);
      a0 += unpack_lo(r0.y) * bf2f(hv.x);
      a1 += unpack_hi(r0.y) * bf2f(hv.y);
      a2 += unpack_lo(r0.z) * bf2f(hv.z);
      a3 += unpack_hi(r0.z) * bf2f(hv.w);
    }
  };

  // chunk 0 (register path)
  {
    float px = expf(e0 - m0), py = expf(e1 - m1);
    float pz = expf(e2 - m2), pw = expf(e3 - m3);
    dn0 += px; dn1 += py; dn2 += pz; dn3 += pw;
    recw[lane] = make_uint4((unsigned)sreg, packbf2(px, py), packbf2(pz, pw), 0u);
    int cnt = re - rs; if (cnt > 64) cnt = 64;
    agg_lds(cnt);
  }
  // extra chunks (deg > 64, rare): recompute e
  for (int base = rs + 64; base < re; base += 64) {
    int s = 0;
    float f0 = NEGBIG, f1 = NEGBIG, f2 = NEGBIG, f3 = NEGBIG;
    if (base + lane < re) {
      s = csr_src[base + lane];
      float4 a = *reinterpret_cast<const float4*>(a_src + (size_t)s * 4);
      f0 = lrelu(a.x + ad4.x); f1 = lrelu(a.y + ad4.y);
      f2 = lrelu(a.z + ad4.z); f3 = lrelu(a.w + ad4.w);
    }
    float px = expf(f0 - m0), py = expf(f1 - m1);
    float pz = expf(f2 - m2), pw = expf(f3 - m3);
    dn0 += px; dn1 += py; dn2 += pz; dn3 += pw;
    recw[lane] = make_uint4((unsigned)s, packbf2(px, py), packbf2(pz, pw), 0u);
    int cnt = re - base; if (cnt > 64) cnt = 64;
    agg_lds(cnt);
  }

  // ---- reduce denom across lanes, add self, invert ----
  #pragma unroll
  for (int off = 32; off > 0; off >>= 1) {
    dn0 += __shfl_xor(dn0, off);
    dn1 += __shfl_xor(dn1, off);
    dn2 += __shfl_xor(dn2, off);
    dn3 += __shfl_xor(dn3, off);
  }
  float sp0 = expf(es0 - m0), sp1 = expf(es1 - m1);
  float sp2 = expf(es2 - m2), sp3 = expf(es3 - m3);
  dn0 += sp0; dn1 += sp1; dn2 += sp2; dn3 += sp3;
  float r0 = 1.f / (dn0 + EPSV), r1 = 1.f / (dn1 + EPSV);
  float r2 = 1.f / (dn2 + EPSV), r3 = 1.f / (dn3 + EPSV);

  // ---- self message + finalize ----
  ushort4 sh = *reinterpret_cast<const ushort4*>(hb16 + (size_t)wid * HC + lane * 4);
  float sum = (a0 + sp0 * bf2f(sh.x)) * r0
            + (a1 + sp1 * bf2f(sh.y)) * r1
            + (a2 + sp2 * bf2f(sh.z)) * r2
            + (a3 + sp3 * bf2f(sh.w)) * r3;
  float v = sum * 0.25f + bias[lane];
  v = fmaxf(v, 0.f);
  if (do_lsm) {
    float mx = v;
    #pragma unroll
    for (int off = 32; off > 0; off >>= 1) mx = fmaxf(mx, __shfl_xor(mx, off));
    float ex = expf(v - mx);
    float sm = ex;
    #pragma unroll
    for (int off = 32; off > 0; off >>= 1) sm += __shfl_xor(sm, off);
    outf[(size_t)wid * CH + lane] = v - mx - logf(sm);
  } else {
    outb[(size_t)wid * CH + lane] = f2bf(v);
  }
}

extern "C" void kernel_launch(void* const* d_in, const int* in_sizes, int n_in,
                              void* d_out, int out_size, void* d_ws, size_t ws_size,
                              hipStream_t stream) {
  const float* x0 = (const float*)d_in[0];
  const int*   ei = (const int*)d_in[1];
  int N = in_sizes[0] / HC;   // 50000
  int E = in_sizes[1] / 2;    // 800000
  const int* srcp = ei;
  const int* dstp = ei + E;

  const float* W[3]  = {(const float*)d_in[2], (const float*)d_in[6],  (const float*)d_in[10]};
  const float* AS[3] = {(const float*)d_in[3], (const float*)d_in[7],  (const float*)d_in[11]};
  const float* AD[3] = {(const float*)d_in[4], (const float*)d_in[8],  (const float*)d_in[12]};
  const float* BI[3] = {(const float*)d_in[5], (const float*)d_in[9],  (const float*)d_in[13]};
  int Kdim[3] = {256, 64, 64};

  char* ws = (char*)d_ws;
  size_t off = 0;
  auto alloc = [&](size_t bytes) {
    void* p = ws + off;
    off += (bytes + 255) & ~(size_t)255;
    return p;
  };
  unsigned short* hb16    = (unsigned short*)alloc((size_t)N * HC * 2); // 25.6 MB
  unsigned short* xb16    = (unsigned short*)alloc((size_t)N * CH * 2); // 6.4 MB
  float*          a_s     = (float*)alloc((size_t)N * 4 * 4);
  float*          a_d     = (float*)alloc((size_t)N * 4 * 4);
  int*            rowp    = (int*)alloc((size_t)(N + 1) * 4);
  int*            cursor  = (int*)alloc((size_t)N * 4);
  int*            csr_src = (int*)alloc((size_t)E * 4);                 // 3.2 MB
  int*            bsum    = (int*)alloc(512 * 4);
  unsigned short* Wt[3];
  Wt[0] = (unsigned short*)alloc((size_t)256 * 256 * 2);
  Wt[1] = (unsigned short*)alloc((size_t)256 * 64 * 2);
  Wt[2] = (unsigned short*)alloc((size_t)256 * 64 * 2);

  // ---- weight prep (bf16 transposed) ----
  for (int L = 0; L < 3; ++L) {
    int tot = Kdim[L] * 256;
    wprep_k<<<(tot + 255) / 256, 256, 0, stream>>>(W[L], Wt[L], Kdim[L]);
  }

  // ---- build CSR by destination (once; reused by all 3 layers) ----
  int nb = (N + 511) / 512;
  zero2_k<<<(N + 255) / 256, 256, 0, stream>>>(cursor, rowp, N);
  hist_k<<<(E + 255) / 256, 256, 0, stream>>>(dstp, rowp, E);
  scan1_k<<<nb, 512, 0, stream>>>(rowp, rowp, bsum, N);
  scan2_k<<<1, 128, 0, stream>>>(bsum, nb);
  scan3_k<<<nb, 512, 0, stream>>>(rowp, bsum, N, E);
  scatter_k<<<(E + 255) / 256, 256, 0, stream>>>(srcp, dstp, rowp, cursor, csr_src, E);

  for (int L = 0; L < 3; ++L) {
    int K = Kdim[L];
    mfma_gat_k<<<(N + 31) / 32, 256, 0, stream>>>(
        (L == 0) ? x0 : nullptr, (L == 0) ? nullptr : xb16,
        Wt[L], AS[L], AD[L], hb16, a_s, a_d, N, K, (L == 0) ? 1 : 0);
    soft_agg_k<<<(N + 3) / 4, 256, 0, stream>>>(rowp, csr_src, a_s, a_d, hb16, BI[L],
                                                (float*)d_out, xb16, N, (L == 2) ? 1 : 0);
  }
}

// Round 9
// 391.789 us; speedup vs baseline: 4.6534x; 1.0262x over previous
//
#include <hip/hip_runtime.h>
#include <hip/hip_bf16.h>
#include <math.h>
#include <stdint.h>

#define HEADS 4
#define CH 64          // channels per head
#define HC 256         // HEADS*CH
#define NEG 0.2f
#define EPSV 1e-16f
#define NEGBIG -3.0e38f

typedef __attribute__((ext_vector_type(8))) short short8;
typedef __attribute__((ext_vector_type(4))) float f32x4;
typedef _Float16 f16_t;
typedef __fp16 fp16x2 __attribute__((ext_vector_type(2)));   // builtin-compatible

__device__ __forceinline__ float lrelu(float x) { return x > 0.f ? x : NEG * x; }

__device__ __forceinline__ unsigned short f2bf(float f) {
  __hip_bfloat16 b = __float2bfloat16(f);   // RNE
  return *reinterpret_cast<unsigned short*>(&b);
}
__device__ __forceinline__ float bf2f(unsigned short u) {
  return __uint_as_float((unsigned)u << 16);
}
// pack two f32 -> packed f16 pair (one v_cvt_pkrtz_f16_f32)
__device__ __forceinline__ unsigned int pkf16(float a, float b) {
  fp16x2 v = __builtin_amdgcn_cvt_pkrtz(a, b);
  return __builtin_bit_cast(unsigned int, v);
}
// acc += dot(packed f16 pair a, packed f16 pair h)
__device__ __forceinline__ float dot2acc(unsigned int a, unsigned int h, float acc) {
#if __has_builtin(__builtin_amdgcn_fdot2)
  return __builtin_amdgcn_fdot2(__builtin_bit_cast(fp16x2, a),
                                __builtin_bit_cast(fp16x2, h), acc, false);
#else
  fp16x2 av = __builtin_bit_cast(fp16x2, a);
  fp16x2 hv = __builtin_bit_cast(fp16x2, h);
  return acc + (float)av[0] * (float)hv[0] + (float)av[1] * (float)hv[1];
#endif
}

// ---------------- weight prep: Wt[n][k] bf16 from W[k][n] f32 ----------------
__global__ __launch_bounds__(256) void wprep_k(const float* __restrict__ W,
                                               unsigned short* __restrict__ Wt,
                                               int K) {
  int i = blockIdx.x * 256 + threadIdx.x;
  if (i >= K * 256) return;
  int k = i >> 8, n = i & 255;
  Wt[(size_t)n * K + k] = f2bf(W[i]);
}

// ---------------- fused MFMA GEMM + attention-dot epilogue ----------------
// h table written in f16, channel-major [node][chan][head].
__global__ __launch_bounds__(256) void mfma_gat_k(const float* __restrict__ Af,
                                                  const unsigned short* __restrict__ Ab,
                                                  const unsigned short* __restrict__ Wt,
                                                  const float* __restrict__ att_s,
                                                  const float* __restrict__ att_d,
                                                  unsigned short* __restrict__ ht16,
                                                  float* __restrict__ a_src,
                                                  float* __restrict__ a_dst,
                                                  int M, int K, int a_is_f32) {
  __shared__ unsigned short As[32 * 40];    // [row][k] stride 40 (pad)
  __shared__ unsigned short Bs[256 * 40];   // [col][k] stride 40
  __shared__ unsigned short Cs[32 * 258];   // [row][chan*4+head] channel-major f16

  int tid = threadIdx.x;
  int bm = blockIdx.x * 32;
  int w = tid >> 6, l = tid & 63;
  int lr = l & 15, lk = l >> 4;
  int row_s = tid >> 3, seg = tid & 7;

  f32x4 acc[2][4];
  #pragma unroll
  for (int rt = 0; rt < 2; ++rt)
    #pragma unroll
    for (int ct = 0; ct < 4; ++ct) {
      f32x4 z = {0.f, 0.f, 0.f, 0.f};
      acc[rt][ct] = z;
    }

  for (int k0 = 0; k0 < K; k0 += 32) {
    if (a_is_f32) {
      float4 v = make_float4(0.f, 0.f, 0.f, 0.f);
      if (bm + row_s < M)
        v = *reinterpret_cast<const float4*>(Af + (size_t)(bm + row_s) * K + k0 + seg * 4);
      ushort4 u;
      u.x = f2bf(v.x); u.y = f2bf(v.y); u.z = f2bf(v.z); u.w = f2bf(v.w);
      *reinterpret_cast<ushort4*>(&As[row_s * 40 + seg * 4]) = u;
    } else {
      ushort4 u = make_ushort4(0, 0, 0, 0);
      if (bm + row_s < M)
        u = *reinterpret_cast<const ushort4*>(Ab + (size_t)(bm + row_s) * K + k0 + seg * 4);
      *reinterpret_cast<ushort4*>(&As[row_s * 40 + seg * 4]) = u;
    }
    {
      const uint4* srcq = reinterpret_cast<const uint4*>(Wt + (size_t)tid * K + k0);
      uint4 q0 = srcq[0], q1 = srcq[1], q2 = srcq[2], q3 = srcq[3];
      uint4* dstq = reinterpret_cast<uint4*>(&Bs[tid * 40]);
      dstq[0] = q0; dstq[1] = q1; dstq[2] = q2; dstq[3] = q3;
    }
    __syncthreads();
    short8 bfr[4];
    #pragma unroll
    for (int ct = 0; ct < 4; ++ct)
      bfr[ct] = *reinterpret_cast<const short8*>(&Bs[(w * 64 + ct * 16 + lr) * 40 + lk * 8]);
    #pragma unroll
    for (int rt = 0; rt < 2; ++rt) {
      short8 af = *reinterpret_cast<const short8*>(&As[(rt * 16 + lr) * 40 + lk * 8]);
      #pragma unroll
      for (int ct = 0; ct < 4; ++ct)
        acc[rt][ct] = __builtin_amdgcn_mfma_f32_16x16x32_bf16(af, bfr[ct], acc[rt][ct], 0, 0, 0);
    }
    __syncthreads();
  }

  #pragma unroll
  for (int rt = 0; rt < 2; ++rt)
    #pragma unroll
    for (int ct = 0; ct < 4; ++ct)
      #pragma unroll
      for (int r = 0; r < 4; ++r) {
        int row = rt * 16 + lk * 4 + r;
        int c = ct * 16 + lr;
        Cs[row * 258 + c * 4 + w] = __builtin_bit_cast(unsigned short, (f16_t)acc[rt][ct][r]);
      }
  __syncthreads();

  if (bm + row_s < M) {
    ushort4* dst = reinterpret_cast<ushort4*>(ht16 + (size_t)(bm + row_s) * HC + seg * 32);
    const unsigned short* srcp = &Cs[row_s * 258 + seg * 32];
    #pragma unroll
    for (int q = 0; q < 4; ++q)
      dst[q] = *reinterpret_cast<const ushort4*>(srcp + q * 4);
  }

  {
    int nd = tid >> 3, q = tid & 7, h = q >> 1, half = q & 1;
    float ps = 0.f, pd = 0.f;
    const float* ats = att_s + h * 64 + half * 32;
    const float* atd = att_d + h * 64 + half * 32;
    const unsigned short* cp = &Cs[nd * 258 + (half * 32) * 4 + h];
    #pragma unroll
    for (int c = 0; c < 32; ++c) {
      float hv = (float)__builtin_bit_cast(f16_t, cp[c * 4]);
      ps += hv * ats[c];
      pd += hv * atd[c];
    }
    ps += __shfl_xor(ps, 1);
    pd += __shfl_xor(pd, 1);
    if (!(q & 1) && bm + nd < M) {
      a_src[(size_t)(bm + nd) * 4 + h] = ps;
      a_dst[(size_t)(bm + nd) * 4 + h] = pd;
    }
  }
}

// ================= CSR build (once per call) =================
__global__ __launch_bounds__(256) void zero2_k(int* __restrict__ a, int* __restrict__ b, int n) {
  int i = blockIdx.x * blockDim.x + threadIdx.x;
  if (i < n) { a[i] = 0; b[i] = 0; }
}

__global__ __launch_bounds__(256) void hist_k(const int* __restrict__ dst, int* __restrict__ count, int E) {
  int e = blockIdx.x * blockDim.x + threadIdx.x;
  if (e < E) atomicAdd(&count[dst[e]], 1);
}

__global__ __launch_bounds__(512) void scan1_k(const int* __restrict__ count,
                                               int* __restrict__ rp,
                                               int* __restrict__ bsum, int n) {
  __shared__ int sh[512];
  int tx = threadIdx.x;
  int i = blockIdx.x * 512 + tx;
  int v = (i < n) ? count[i] : 0;
  sh[tx] = v;
  __syncthreads();
  #pragma unroll
  for (int off = 1; off < 512; off <<= 1) {
    int t = (tx >= off) ? sh[tx - off] : 0;
    __syncthreads();
    sh[tx] += t;
    __syncthreads();
  }
  if (i < n) rp[i] = sh[tx] - v;          // exclusive
  if (tx == 511) bsum[blockIdx.x] = sh[511];
}

__global__ __launch_bounds__(128) void scan2_k(int* __restrict__ bsum, int nb) {
  __shared__ int sh[128];
  int tx = threadIdx.x;
  int v = (tx < nb) ? bsum[tx] : 0;
  sh[tx] = v;
  __syncthreads();
  #pragma unroll
  for (int off = 1; off < 128; off <<= 1) {
    int t = (tx >= off) ? sh[tx - off] : 0;
    __syncthreads();
    sh[tx] += t;
    __syncthreads();
  }
  if (tx < nb) bsum[tx] = sh[tx] - v;      // exclusive
}

__global__ __launch_bounds__(512) void scan3_k(int* __restrict__ rp, const int* __restrict__ bsum,
                                               int n, int E) {
  int i = blockIdx.x * 512 + threadIdx.x;
  if (i < n) rp[i] += bsum[blockIdx.x];
  if (i == 0) rp[n] = E;
}

__global__ __launch_bounds__(256) void scatter_k(const int* __restrict__ src, const int* __restrict__ dst,
                                                 const int* __restrict__ rp, int* __restrict__ cursor,
                                                 int* __restrict__ csr_src, int E) {
  int e = blockIdx.x * blockDim.x + threadIdx.x;
  if (e >= E) return;
  int d = dst[e];
  int pos = rp[d] + atomicAdd(&cursor[d], 1);
  csr_src[pos] = src[e];
}

// ------------- FUSED segment softmax + gather-aggregate + finalize -------------
// One wave per node. Denominator reduced BEFORE aggregation so alpha = p/denom
// is folded per edge; aggregation is one f32 accumulator fed by 2 v_dot2_f32_f16
// per edge on packed f16 (alpha, h). Gather base scalarized via readfirstlane.
__global__ __launch_bounds__(256) void soft_agg_k(const int* __restrict__ rp,
                                                  const int* __restrict__ csr_src,
                                                  const float* __restrict__ a_src,
                                                  const float* __restrict__ a_dst,
                                                  const unsigned short* __restrict__ ht16,
                                                  const float* __restrict__ bias,
                                                  float* __restrict__ outf,
                                                  unsigned short* __restrict__ outb,
                                                  int N, int do_lsm) {
  __shared__ uint4 rec[4][64];              // per-wave private 64 edge records
  int tid  = threadIdx.x;
  int w    = tid >> 6;
  int lane = tid & 63;
  int wid  = (blockIdx.x * blockDim.x + tid) >> 6;
  if (wid >= N) return;
  int rs = rp[wid], re = rp[wid + 1];

  float4 ad4 = *reinterpret_cast<const float4*>(a_dst + (size_t)wid * 4);
  float4 asn = *reinterpret_cast<const float4*>(a_src + (size_t)wid * 4);
  float es0 = lrelu(asn.x + ad4.x), es1 = lrelu(asn.y + ad4.y);
  float es2 = lrelu(asn.z + ad4.z), es3 = lrelu(asn.w + ad4.w);

  // ---- phase A: per-lane e for chunk 0 (registers), max over all edges ----
  int sreg = 0;
  float e0 = NEGBIG, e1 = NEGBIG, e2 = NEGBIG, e3 = NEGBIG;
  if (rs + lane < re) {
    sreg = csr_src[rs + lane];
    float4 a = *reinterpret_cast<const float4*>(a_src + (size_t)sreg * 4);
    e0 = lrelu(a.x + ad4.x); e1 = lrelu(a.y + ad4.y);
    e2 = lrelu(a.z + ad4.z); e3 = lrelu(a.w + ad4.w);
  }
  float m0 = fmaxf(es0, e0), m1 = fmaxf(es1, e1);
  float m2 = fmaxf(es2, e2), m3 = fmaxf(es3, e3);
  for (int base = rs + 64; base < re; base += 64) {   // rare (deg > 64)
    if (base + lane < re) {
      int s = csr_src[base + lane];
      float4 a = *reinterpret_cast<const float4*>(a_src + (size_t)s * 4);
      m0 = fmaxf(m0, lrelu(a.x + ad4.x)); m1 = fmaxf(m1, lrelu(a.y + ad4.y));
      m2 = fmaxf(m2, lrelu(a.z + ad4.z)); m3 = fmaxf(m3, lrelu(a.w + ad4.w));
    }
  }
  #pragma unroll
  for (int off = 32; off > 0; off >>= 1) {
    m0 = fmaxf(m0, __shfl_xor(m0, off));
    m1 = fmaxf(m1, __shfl_xor(m1, off));
    m2 = fmaxf(m2, __shfl_xor(m2, off));
    m3 = fmaxf(m3, __shfl_xor(m3, off));
  }

  // ---- phase B: denominators (chunk-0 p stays in registers) ----
  float px = expf(e0 - m0), py = expf(e1 - m1);
  float pz = expf(e2 - m2), pw = expf(e3 - m3);
  float dn0 = px, dn1 = py, dn2 = pz, dn3 = pw;
  for (int base = rs + 64; base < re; base += 64) {   // rare
    if (base + lane < re) {
      int s = csr_src[base + lane];
      float4 a = *reinterpret_cast<const float4*>(a_src + (size_t)s * 4);
      dn0 += expf(lrelu(a.x + ad4.x) - m0); dn1 += expf(lrelu(a.y + ad4.y) - m1);
      dn2 += expf(lrelu(a.z + ad4.z) - m2); dn3 += expf(lrelu(a.w + ad4.w) - m3);
    }
  }
  #pragma unroll
  for (int off = 32; off > 0; off >>= 1) {
    dn0 += __shfl_xor(dn0, off);
    dn1 += __shfl_xor(dn1, off);
    dn2 += __shfl_xor(dn2, off);
    dn3 += __shfl_xor(dn3, off);
  }
  float sp0 = expf(es0 - m0), sp1 = expf(es1 - m1);
  float sp2 = expf(es2 - m2), sp3 = expf(es3 - m3);
  dn0 += sp0; dn1 += sp1; dn2 += sp2; dn3 += sp3;
  float rr0 = 1.f / (dn0 + EPSV), rr1 = 1.f / (dn1 + EPSV);
  float rr2 = 1.f / (dn2 + EPSV), rr3 = 1.f / (dn3 + EPSV);

  // ---- phase C: alpha = p*r packed f16 into LDS records; dot2 aggregation ----
  float acc = 0.f;
  uint4* recw = &rec[w][0];
  const unsigned short* hl = ht16 + lane * 4;   // per-lane channel offset

  auto agg_lds = [&](int cnt) {
    int k = 0;
    for (; k + 4 <= cnt; k += 4) {
      uint4 r0 = recw[k + 0], r1 = recw[k + 1], r2 = recw[k + 2], r3 = recw[k + 3];
      int s0 = __builtin_amdgcn_readfirstlane((int)r0.x);
      int s1 = __builtin_amdgcn_readfirstlane((int)r1.x);
      int s2 = __builtin_amdgcn_readfirstlane((int)r2.x);
      int s3 = __builtin_amdgcn_readfirstlane((int)r3.x);
      uint2 h0 = *reinterpret_cast<const uint2*>(hl + (size_t)s0 * HC);
      uint2 h1 = *reinterpret_cast<const uint2*>(hl + (size_t)s1 * HC);
      uint2 h2 = *reinterpret_cast<const uint2*>(hl + (size_t)s2 * HC);
      uint2 h3 = *reinterpret_cast<const uint2*>(hl + (size_t)s3 * HC);
      acc = dot2acc(r0.y, h0.x, acc); acc = dot2acc(r0.z, h0.y, acc);
      acc = dot2acc(r1.y, h1.x, acc); acc = dot2acc(r1.z, h1.y, acc);
      acc = dot2acc(r2.y, h2.x, acc); acc = dot2acc(r2.z, h2.y, acc);
      acc = dot2acc(r3.y, h3.x, acc); acc = dot2acc(r3.z, h3.y, acc);
    }
    for (; k < cnt; ++k) {
      uint4 r0 = recw[k];
      int s0 = __builtin_amdgcn_readfirstlane((int)r0.x);
      uint2 hv = *reinterpret_cast<const uint2*>(hl + (size_t)s0 * HC);
      acc = dot2acc(r0.y, hv.x, acc);
      acc = dot2acc(r0.z, hv.y, acc);
    }
  };

  // chunk 0 (register path)
  {
    recw[lane] = make_uint4((unsigned)sreg, pkf16(px * rr0, py * rr1),
                            pkf16(pz * rr2, pw * rr3), 0u);
    int cnt = re - rs; if (cnt > 64) cnt = 64;
    agg_lds(cnt);
  }
  // extra chunks (deg > 64, rare): recompute e
  for (int base = rs + 64; base < re; base += 64) {
    int s = 0;
    float f0 = NEGBIG, f1 = NEGBIG, f2 = NEGBIG, f3 = NEGBIG;
    if (base + lane < re) {
      s = csr_src[base + lane];
      float4 a = *reinterpret_cast<const float4*>(a_src + (size_t)s * 4);
      f0 = lrelu(a.x + ad4.x); f1 = lrelu(a.y + ad4.y);
      f2 = lrelu(a.z + ad4.z); f3 = lrelu(a.w + ad4.w);
    }
    float qx = expf(f0 - m0) * rr0, qy = expf(f1 - m1) * rr1;
    float qz = expf(f2 - m2) * rr2, qw = expf(f3 - m3) * rr3;
    recw[lane] = make_uint4((unsigned)s, pkf16(qx, qy), pkf16(qz, qw), 0u);
    int cnt = re - base; if (cnt > 64) cnt = 64;
    agg_lds(cnt);
  }

  // ---- self message + finalize ----
  uint2 shv = *reinterpret_cast<const uint2*>(ht16 + (size_t)wid * HC + lane * 4);
  acc = dot2acc(pkf16(sp0 * rr0, sp1 * rr1), shv.x, acc);
  acc = dot2acc(pkf16(sp2 * rr2, sp3 * rr3), shv.y, acc);
  float v = acc * 0.25f + bias[lane];
  v = fmaxf(v, 0.f);
  if (do_lsm) {
    float mx = v;
    #pragma unroll
    for (int off = 32; off > 0; off >>= 1) mx = fmaxf(mx, __shfl_xor(mx, off));
    float ex = expf(v - mx);
    float sm = ex;
    #pragma unroll
    for (int off = 32; off > 0; off >>= 1) sm += __shfl_xor(sm, off);
    outf[(size_t)wid * CH + lane] = v - mx - logf(sm);
  } else {
    outb[(size_t)wid * CH + lane] = f2bf(v);
  }
}

extern "C" void kernel_launch(void* const* d_in, const int* in_sizes, int n_in,
                              void* d_out, int out_size, void* d_ws, size_t ws_size,
                              hipStream_t stream) {
  const float* x0 = (const float*)d_in[0];
  const int*   ei = (const int*)d_in[1];
  int N = in_sizes[0] / HC;   // 50000
  int E = in_sizes[1] / 2;    // 800000
  const int* srcp = ei;
  const int* dstp = ei + E;

  const float* W[3]  = {(const float*)d_in[2], (const float*)d_in[6],  (const float*)d_in[10]};
  const float* AS[3] = {(const float*)d_in[3], (const float*)d_in[7],  (const float*)d_in[11]};
  const float* AD[3] = {(const float*)d_in[4], (const float*)d_in[8],  (const float*)d_in[12]};
  const float* BI[3] = {(const float*)d_in[5], (const float*)d_in[9],  (const float*)d_in[13]};
  int Kdim[3] = {256, 64, 64};

  char* ws = (char*)d_ws;
  size_t off = 0;
  auto alloc = [&](size_t bytes) {
    void* p = ws + off;
    off += (bytes + 255) & ~(size_t)255;
    return p;
  };
  unsigned short* ht16    = (unsigned short*)alloc((size_t)N * HC * 2); // 25.6 MB (f16)
  unsigned short* xb16    = (unsigned short*)alloc((size_t)N * CH * 2); // 6.4 MB (bf16)
  float*          a_s     = (float*)alloc((size_t)N * 4 * 4);
  float*          a_d     = (float*)alloc((size_t)N * 4 * 4);
  int*            rowp    = (int*)alloc((size_t)(N + 1) * 4);
  int*            cursor  = (int*)alloc((size_t)N * 4);
  int*            csr_src = (int*)alloc((size_t)E * 4);                 // 3.2 MB
  int*            bsum    = (int*)alloc(512 * 4);
  unsigned short* Wt[3];
  Wt[0] = (unsigned short*)alloc((size_t)256 * 256 * 2);
  Wt[1] = (unsigned short*)alloc((size_t)256 * 64 * 2);
  Wt[2] = (unsigned short*)alloc((size_t)256 * 64 * 2);

  // ---- weight prep (bf16 transposed) ----
  for (int L = 0; L < 3; ++L) {
    int tot = Kdim[L] * 256;
    wprep_k<<<(tot + 255) / 256, 256, 0, stream>>>(W[L], Wt[L], Kdim[L]);
  }

  // ---- build CSR by destination (once; reused by all 3 layers) ----
  int nb = (N + 511) / 512;
  zero2_k<<<(N + 255) / 256, 256, 0, stream>>>(cursor, rowp, N);
  hist_k<<<(E + 255) / 256, 256, 0, stream>>>(dstp, rowp, E);
  scan1_k<<<nb, 512, 0, stream>>>(rowp, rowp, bsum, N);
  scan2_k<<<1, 128, 0, stream>>>(bsum, nb);
  scan3_k<<<nb, 512, 0, stream>>>(rowp, bsum, N, E);
  scatter_k<<<(E + 255) / 256, 256, 0, stream>>>(srcp, dstp, rowp, cursor, csr_src, E);

  for (int L = 0; L < 3; ++L) {
    int K = Kdim[L];
    mfma_gat_k<<<(N + 31) / 32, 256, 0, stream>>>(
        (L == 0) ? x0 : nullptr, (L == 0) ? nullptr : xb16,
        Wt[L], AS[L], AD[L], ht16, a_s, a_d, N, K, (L == 0) ? 1 : 0);
    soft_agg_k<<<(N + 3) / 4, 256, 0, stream>>>(rowp, csr_src, a_s, a_d, ht16, BI[L],
                                                (float*)d_out, xb16, N, (L == 2) ? 1 : 0);
  }
}

// Round 10
// 383.861 us; speedup vs baseline: 4.7495x; 1.0207x over previous
//
#include <hip/hip_runtime.h>
#include <hip/hip_bf16.h>
#include <math.h>
#include <stdint.h>

#define HEADS 4
#define CH 64          // channels per head
#define HC 256         // HEADS*CH
#define NEG 0.2f
#define EPSV 1e-16f
#define NEGBIG -3.0e38f

typedef __attribute__((ext_vector_type(8))) short short8;
typedef __attribute__((ext_vector_type(4))) float f32x4;
typedef _Float16 f16_t;
typedef __fp16 fp16x2 __attribute__((ext_vector_type(2)));   // builtin-compatible

__device__ __forceinline__ float lrelu(float x) { return x > 0.f ? x : NEG * x; }

__device__ __forceinline__ unsigned short f2bf(float f) {
  __hip_bfloat16 b = __float2bfloat16(f);   // RNE
  return *reinterpret_cast<unsigned short*>(&b);
}
__device__ __forceinline__ unsigned short f16b(float f) {
  return __builtin_bit_cast(unsigned short, (f16_t)f);
}
// acc += dot(packed f16 pair a, packed f16 pair h)
__device__ __forceinline__ float dot2acc(unsigned int a, unsigned int h, float acc) {
#if __has_builtin(__builtin_amdgcn_fdot2)
  return __builtin_amdgcn_fdot2(__builtin_bit_cast(fp16x2, a),
                                __builtin_bit_cast(fp16x2, h), acc, false);
#else
  fp16x2 av = __builtin_bit_cast(fp16x2, a);
  fp16x2 hv = __builtin_bit_cast(fp16x2, h);
  return acc + (float)av[0] * (float)hv[0] + (float)av[1] * (float)hv[1];
#endif
}

// ---------------- weight prep: Wt[n][k] bf16 from W[k][n] f32 ----------------
__global__ __launch_bounds__(256) void wprep_k(const float* __restrict__ W,
                                               unsigned short* __restrict__ Wt,
                                               int K) {
  int i = blockIdx.x * 256 + threadIdx.x;
  if (i >= K * 256) return;
  int k = i >> 8, n = i & 255;
  Wt[(size_t)n * K + k] = f2bf(W[i]);
}

// ---------------- fused MFMA GEMM + attention-dot epilogue ----------------
// h table written in f16, channel-major [node][chan][head].
__global__ __launch_bounds__(256) void mfma_gat_k(const float* __restrict__ Af,
                                                  const unsigned short* __restrict__ Ab,
                                                  const unsigned short* __restrict__ Wt,
                                                  const float* __restrict__ att_s,
                                                  const float* __restrict__ att_d,
                                                  unsigned short* __restrict__ ht16,
                                                  float* __restrict__ a_src,
                                                  float* __restrict__ a_dst,
                                                  int M, int K, int a_is_f32) {
  __shared__ unsigned short As[32 * 40];    // [row][k] stride 40 (pad)
  __shared__ unsigned short Bs[256 * 40];   // [col][k] stride 40
  __shared__ unsigned short Cs[32 * 258];   // [row][chan*4+head] channel-major f16

  int tid = threadIdx.x;
  int bm = blockIdx.x * 32;
  int w = tid >> 6, l = tid & 63;
  int lr = l & 15, lk = l >> 4;
  int row_s = tid >> 3, seg = tid & 7;

  f32x4 acc[2][4];
  #pragma unroll
  for (int rt = 0; rt < 2; ++rt)
    #pragma unroll
    for (int ct = 0; ct < 4; ++ct) {
      f32x4 z = {0.f, 0.f, 0.f, 0.f};
      acc[rt][ct] = z;
    }

  for (int k0 = 0; k0 < K; k0 += 32) {
    if (a_is_f32) {
      float4 v = make_float4(0.f, 0.f, 0.f, 0.f);
      if (bm + row_s < M)
        v = *reinterpret_cast<const float4*>(Af + (size_t)(bm + row_s) * K + k0 + seg * 4);
      ushort4 u;
      u.x = f2bf(v.x); u.y = f2bf(v.y); u.z = f2bf(v.z); u.w = f2bf(v.w);
      *reinterpret_cast<ushort4*>(&As[row_s * 40 + seg * 4]) = u;
    } else {
      ushort4 u = make_ushort4(0, 0, 0, 0);
      if (bm + row_s < M)
        u = *reinterpret_cast<const ushort4*>(Ab + (size_t)(bm + row_s) * K + k0 + seg * 4);
      *reinterpret_cast<ushort4*>(&As[row_s * 40 + seg * 4]) = u;
    }
    {
      const uint4* srcq = reinterpret_cast<const uint4*>(Wt + (size_t)tid * K + k0);
      uint4 q0 = srcq[0], q1 = srcq[1], q2 = srcq[2], q3 = srcq[3];
      uint4* dstq = reinterpret_cast<uint4*>(&Bs[tid * 40]);
      dstq[0] = q0; dstq[1] = q1; dstq[2] = q2; dstq[3] = q3;
    }
    __syncthreads();
    short8 bfr[4];
    #pragma unroll
    for (int ct = 0; ct < 4; ++ct)
      bfr[ct] = *reinterpret_cast<const short8*>(&Bs[(w * 64 + ct * 16 + lr) * 40 + lk * 8]);
    #pragma unroll
    for (int rt = 0; rt < 2; ++rt) {
      short8 af = *reinterpret_cast<const short8*>(&As[(rt * 16 + lr) * 40 + lk * 8]);
      #pragma unroll
      for (int ct = 0; ct < 4; ++ct)
        acc[rt][ct] = __builtin_amdgcn_mfma_f32_16x16x32_bf16(af, bfr[ct], acc[rt][ct], 0, 0, 0);
    }
    __syncthreads();
  }

  #pragma unroll
  for (int rt = 0; rt < 2; ++rt)
    #pragma unroll
    for (int ct = 0; ct < 4; ++ct)
      #pragma unroll
      for (int r = 0; r < 4; ++r) {
        int row = rt * 16 + lk * 4 + r;
        int c = ct * 16 + lr;
        Cs[row * 258 + c * 4 + w] = f16b(acc[rt][ct][r]);
      }
  __syncthreads();

  if (bm + row_s < M) {
    ushort4* dst = reinterpret_cast<ushort4*>(ht16 + (size_t)(bm + row_s) * HC + seg * 32);
    const unsigned short* srcp = &Cs[row_s * 258 + seg * 32];
    #pragma unroll
    for (int q = 0; q < 4; ++q)
      dst[q] = *reinterpret_cast<const ushort4*>(srcp + q * 4);
  }

  {
    int nd = tid >> 3, q = tid & 7, h = q >> 1, half = q & 1;
    float ps = 0.f, pd = 0.f;
    const float* ats = att_s + h * 64 + half * 32;
    const float* atd = att_d + h * 64 + half * 32;
    const unsigned short* cp = &Cs[nd * 258 + (half * 32) * 4 + h];
    #pragma unroll
    for (int c = 0; c < 32; ++c) {
      float hv = (float)__builtin_bit_cast(f16_t, cp[c * 4]);
      ps += hv * ats[c];
      pd += hv * atd[c];
    }
    ps += __shfl_xor(ps, 1);
    pd += __shfl_xor(pd, 1);
    if (!(q & 1) && bm + nd < M) {
      a_src[(size_t)(bm + nd) * 4 + h] = ps;
      a_dst[(size_t)(bm + nd) * 4 + h] = pd;
    }
  }
}

// ================= CSR build (once per call) =================
__global__ __launch_bounds__(256) void zero2_k(int* __restrict__ a, int* __restrict__ b, int n) {
  int i = blockIdx.x * blockDim.x + threadIdx.x;
  if (i < n) { a[i] = 0; b[i] = 0; }
}

__global__ __launch_bounds__(256) void hist_k(const int* __restrict__ dst, int* __restrict__ count, int E) {
  int e = blockIdx.x * blockDim.x + threadIdx.x;
  if (e < E) atomicAdd(&count[dst[e]], 1);
}

__global__ __launch_bounds__(512) void scan1_k(const int* __restrict__ count,
                                               int* __restrict__ rp,
                                               int* __restrict__ bsum, int n) {
  __shared__ int sh[512];
  int tx = threadIdx.x;
  int i = blockIdx.x * 512 + tx;
  int v = (i < n) ? count[i] : 0;
  sh[tx] = v;
  __syncthreads();
  #pragma unroll
  for (int off = 1; off < 512; off <<= 1) {
    int t = (tx >= off) ? sh[tx - off] : 0;
    __syncthreads();
    sh[tx] += t;
    __syncthreads();
  }
  if (i < n) rp[i] = sh[tx] - v;          // exclusive
  if (tx == 511) bsum[blockIdx.x] = sh[511];
}

__global__ __launch_bounds__(128) void scan2_k(int* __restrict__ bsum, int nb) {
  __shared__ int sh[128];
  int tx = threadIdx.x;
  int v = (tx < nb) ? bsum[tx] : 0;
  sh[tx] = v;
  __syncthreads();
  #pragma unroll
  for (int off = 1; off < 128; off <<= 1) {
    int t = (tx >= off) ? sh[tx - off] : 0;
    __syncthreads();
    sh[tx] += t;
    __syncthreads();
  }
  if (tx < nb) bsum[tx] = sh[tx] - v;      // exclusive
}

__global__ __launch_bounds__(512) void scan3_k(int* __restrict__ rp, const int* __restrict__ bsum,
                                               int n, int E) {
  int i = blockIdx.x * 512 + threadIdx.x;
  if (i < n) rp[i] += bsum[blockIdx.x];
  if (i == 0) rp[n] = E;
}

__global__ __launch_bounds__(256) void scatter_k(const int* __restrict__ src, const int* __restrict__ dst,
                                                 const int* __restrict__ rp, int* __restrict__ cursor,
                                                 int* __restrict__ csr_src, int E) {
  int e = blockIdx.x * blockDim.x + threadIdx.x;
  if (e >= E) return;
  int d = dst[e];
  int pos = rp[d] + atomicAdd(&cursor[d], 1);
  csr_src[pos] = src[e];
}

// ------------- FUSED segment softmax + gather-aggregate + finalize -------------
// One wave per node. Lane = (edge_slot, head) = (lane&15, lane>>4):
// 16-wide scalar reductions (4 shuffles each) instead of 64-wide x4.
// Chunks 0+1 (32 edges, ~100% of Poisson(16) degrees) register-cached.
// Alphas packed as f16 into per-edge 16B LDS records {a_h0..h3, s};
// aggregation reads records at wave-uniform addresses, gather base
// scalarized via readfirstlane, 2x fdot2 per edge.
__global__ __launch_bounds__(256) void soft_agg_k(const int* __restrict__ rp,
                                                  const int* __restrict__ csr_src,
                                                  const float* __restrict__ a_src,
                                                  const float* __restrict__ a_dst,
                                                  const unsigned short* __restrict__ ht16,
                                                  const float* __restrict__ bias,
                                                  float* __restrict__ outf,
                                                  unsigned short* __restrict__ outb,
                                                  int N, int do_lsm) {
  __shared__ uint4 rec[4][17];              // 16 edge records + self record per wave
  int tid  = threadIdx.x;
  int w    = tid >> 6;
  int lane = tid & 63;
  int wid  = (blockIdx.x * blockDim.x + tid) >> 6;
  if (wid >= N) return;
  int rs = rp[wid], re = rp[wid + 1];
  int ep = lane & 15;          // edge slot in chunk
  int h  = lane >> 4;          // head

  float adh = a_dst[(size_t)wid * 4 + h];
  float ash = a_src[(size_t)wid * 4 + h];
  float es  = lrelu(ash + adh);

  // ---- phase A: max over all edges (chunks 0,1 cached in regs) ----
  int s0 = 0, s1 = 0;
  float e0 = NEGBIG, e1 = NEGBIG;
  if (rs + ep < re) {
    s0 = csr_src[rs + ep];
    e0 = lrelu(a_src[(size_t)s0 * 4 + h] + adh);
  }
  if (rs + 16 + ep < re) {
    s1 = csr_src[rs + 16 + ep];
    e1 = lrelu(a_src[(size_t)s1 * 4 + h] + adh);
  }
  float m = fmaxf(es, fmaxf(e0, e1));
  for (int base = rs + 32; base < re; base += 16) {   // rare (deg > 32)
    if (base + ep < re) {
      int s = csr_src[base + ep];
      m = fmaxf(m, lrelu(a_src[(size_t)s * 4 + h] + adh));
    }
  }
  #pragma unroll
  for (int off = 8; off > 0; off >>= 1) m = fmaxf(m, __shfl_xor(m, off));

  // ---- phase B: denominator (p0,p1 stay in regs) ----
  float p0 = expf(e0 - m), p1 = expf(e1 - m);         // 0 for invalid slots
  float dn = p0 + p1;
  for (int base = rs + 32; base < re; base += 16) {   // rare
    if (base + ep < re) {
      int s = csr_src[base + ep];
      dn += expf(lrelu(a_src[(size_t)s * 4 + h] + adh) - m);
    }
  }
  #pragma unroll
  for (int off = 8; off > 0; off >>= 1) dn += __shfl_xor(dn, off);
  float sp = expf(es - m);
  dn += sp;
  float rr = 1.f / (dn + EPSV);

  // ---- phase C: alpha records in LDS + dot2 aggregation ----
  // record e (16B): bytes0-7 alpha f16 x4 (head h at byte 2h), bytes8-11 s
  unsigned short* recb = reinterpret_cast<unsigned short*>(&rec[w][0]);
  float acc = 0.f;
  const unsigned short* hl = ht16 + lane * 4;   // lane = channel in agg phase

  auto agg = [&](int cnt) {
    int k = 0;
    for (; k + 4 <= cnt; k += 4) {
      uint4 r0 = rec[w][k + 0], r1 = rec[w][k + 1];
      uint4 r2 = rec[w][k + 2], r3 = rec[w][k + 3];
      int t0 = __builtin_amdgcn_readfirstlane((int)r0.z);
      int t1 = __builtin_amdgcn_readfirstlane((int)r1.z);
      int t2 = __builtin_amdgcn_readfirstlane((int)r2.z);
      int t3 = __builtin_amdgcn_readfirstlane((int)r3.z);
      uint2 h0 = *reinterpret_cast<const uint2*>(hl + (size_t)t0 * HC);
      uint2 h1 = *reinterpret_cast<const uint2*>(hl + (size_t)t1 * HC);
      uint2 h2 = *reinterpret_cast<const uint2*>(hl + (size_t)t2 * HC);
      uint2 h3 = *reinterpret_cast<const uint2*>(hl + (size_t)t3 * HC);
      acc = dot2acc(r0.x, h0.x, acc); acc = dot2acc(r0.y, h0.y, acc);
      acc = dot2acc(r1.x, h1.x, acc); acc = dot2acc(r1.y, h1.y, acc);
      acc = dot2acc(r2.x, h2.x, acc); acc = dot2acc(r2.y, h2.y, acc);
      acc = dot2acc(r3.x, h3.x, acc); acc = dot2acc(r3.y, h3.y, acc);
    }
    for (; k < cnt; ++k) {
      uint4 r0 = rec[w][k];
      int t0 = __builtin_amdgcn_readfirstlane((int)r0.z);
      uint2 hv = *reinterpret_cast<const uint2*>(hl + (size_t)t0 * HC);
      acc = dot2acc(r0.x, hv.x, acc);
      acc = dot2acc(r0.y, hv.y, acc);
    }
  };

  // self record (slot 16) + chunk 0
  if (ep == 0) recb[16 * 8 + h] = f16b(sp * rr);
  recb[ep * 8 + h] = f16b(p0 * rr);
  if (h == 0) *reinterpret_cast<int*>(recb + ep * 8 + 4) = s0;
  {
    int cnt = re - rs; if (cnt > 16) cnt = 16;
    agg(cnt);
  }
  // chunk 1 (register-cached)
  if (re > rs + 16) {
    recb[ep * 8 + h] = f16b(p1 * rr);
    if (h == 0) *reinterpret_cast<int*>(recb + ep * 8 + 4) = s1;
    int cnt = re - rs - 16; if (cnt > 16) cnt = 16;
    agg(cnt);
  }
  // extra chunks (deg > 32, rare): recompute
  for (int base = rs + 32; base < re; base += 16) {
    int s = 0;
    float e = NEGBIG;
    if (base + ep < re) {
      s = csr_src[base + ep];
      e = lrelu(a_src[(size_t)s * 4 + h] + adh);
    }
    recb[ep * 8 + h] = f16b(expf(e - m) * rr);
    if (h == 0) *reinterpret_cast<int*>(recb + ep * 8 + 4) = s;
    int cnt = re - base; if (cnt > 16) cnt = 16;
    agg(cnt);
  }

  // ---- self message + finalize ----
  uint2 sa = *reinterpret_cast<const uint2*>(&rec[w][16]);   // uniform
  uint2 shv = *reinterpret_cast<const uint2*>(ht16 + (size_t)wid * HC + lane * 4);
  acc = dot2acc(sa.x, shv.x, acc);
  acc = dot2acc(sa.y, shv.y, acc);
  float v = acc * 0.25f + bias[lane];
  v = fmaxf(v, 0.f);
  if (do_lsm) {
    float mx = v;
    #pragma unroll
    for (int off = 32; off > 0; off >>= 1) mx = fmaxf(mx, __shfl_xor(mx, off));
    float ex = expf(v - mx);
    float sm = ex;
    #pragma unroll
    for (int off = 32; off > 0; off >>= 1) sm += __shfl_xor(sm, off);
    outf[(size_t)wid * CH + lane] = v - mx - logf(sm);
  } else {
    outb[(size_t)wid * CH + lane] = f2bf(v);
  }
}

extern "C" void kernel_launch(void* const* d_in, const int* in_sizes, int n_in,
                              void* d_out, int out_size, void* d_ws, size_t ws_size,
                              hipStream_t stream) {
  const float* x0 = (const float*)d_in[0];
  const int*   ei = (const int*)d_in[1];
  int N = in_sizes[0] / HC;   // 50000
  int E = in_sizes[1] / 2;    // 800000
  const int* srcp = ei;
  const int* dstp = ei + E;

  const float* W[3]  = {(const float*)d_in[2], (const float*)d_in[6],  (const float*)d_in[10]};
  const float* AS[3] = {(const float*)d_in[3], (const float*)d_in[7],  (const float*)d_in[11]};
  const float* AD[3] = {(const float*)d_in[4], (const float*)d_in[8],  (const float*)d_in[12]};
  const float* BI[3] = {(const float*)d_in[5], (const float*)d_in[9],  (const float*)d_in[13]};
  int Kdim[3] = {256, 64, 64};

  char* ws = (char*)d_ws;
  size_t off = 0;
  auto alloc = [&](size_t bytes) {
    void* p = ws + off;
    off += (bytes + 255) & ~(size_t)255;
    return p;
  };
  unsigned short* ht16    = (unsigned short*)alloc((size_t)N * HC * 2); // 25.6 MB (f16)
  unsigned short* xb16    = (unsigned short*)alloc((size_t)N * CH * 2); // 6.4 MB (bf16)
  float*          a_s     = (float*)alloc((size_t)N * 4 * 4);
  float*          a_d     = (float*)alloc((size_t)N * 4 * 4);
  int*            rowp    = (int*)alloc((size_t)(N + 1) * 4);
  int*            cursor  = (int*)alloc((size_t)N * 4);
  int*            csr_src = (int*)alloc((size_t)E * 4);                 // 3.2 MB
  int*            bsum    = (int*)alloc(512 * 4);
  unsigned short* Wt[3];
  Wt[0] = (unsigned short*)alloc((size_t)256 * 256 * 2);
  Wt[1] = (unsigned short*)alloc((size_t)256 * 64 * 2);
  Wt[2] = (unsigned short*)alloc((size_t)256 * 64 * 2);

  // ---- weight prep (bf16 transposed) ----
  for (int L = 0; L < 3; ++L) {
    int tot = Kdim[L] * 256;
    wprep_k<<<(tot + 255) / 256, 256, 0, stream>>>(W[L], Wt[L], Kdim[L]);
  }

  // ---- build CSR by destination (once; reused by all 3 layers) ----
  int nb = (N + 511) / 512;
  zero2_k<<<(N + 255) / 256, 256, 0, stream>>>(cursor, rowp, N);
  hist_k<<<(E + 255) / 256, 256, 0, stream>>>(dstp, rowp, E);
  scan1_k<<<nb, 512, 0, stream>>>(rowp, rowp, bsum, N);
  scan2_k<<<1, 128, 0, stream>>>(bsum, nb);
  scan3_k<<<nb, 512, 0, stream>>>(rowp, bsum, N, E);
  scatter_k<<<(E + 255) / 256, 256, 0, stream>>>(srcp, dstp, rowp, cursor, csr_src, E);

  for (int L = 0; L < 3; ++L) {
    int K = Kdim[L];
    mfma_gat_k<<<(N + 31) / 32, 256, 0, stream>>>(
        (L == 0) ? x0 : nullptr, (L == 0) ? nullptr : xb16,
        Wt[L], AS[L], AD[L], ht16, a_s, a_d, N, K, (L == 0) ? 1 : 0);
    soft_agg_k<<<(N + 3) / 4, 256, 0, stream>>>(rowp, csr_src, a_s, a_d, ht16, BI[L],
                                                (float*)d_out, xb16, N, (L == 2) ? 1 : 0);
  }
}

// Round 11
// 383.197 us; speedup vs baseline: 4.7578x; 1.0017x over previous
//
#include <hip/hip_runtime.h>
#include <hip/hip_bf16.h>
#include <math.h>
#include <stdint.h>

#define HEADS 4
#define CH 64          // channels per head
#define HC 256         // HEADS*CH
#define NEG 0.2f
#define EPSV 1e-16f
#define NEGBIG -3.0e38f

typedef __attribute__((ext_vector_type(8))) short short8;
typedef __attribute__((ext_vector_type(4))) float f32x4;
typedef _Float16 f16_t;
typedef __fp16 fp16x2 __attribute__((ext_vector_type(2)));   // builtin-compatible

__device__ __forceinline__ float lrelu(float x) { return x > 0.f ? x : NEG * x; }

__device__ __forceinline__ unsigned short f2bf(float f) {
  __hip_bfloat16 b = __float2bfloat16(f);   // RNE
  return *reinterpret_cast<unsigned short*>(&b);
}
__device__ __forceinline__ unsigned short f16b(float f) {
  return __builtin_bit_cast(unsigned short, (f16_t)f);
}
// acc += dot(packed f16 pair a, packed f16 pair h)
__device__ __forceinline__ float dot2acc(unsigned int a, unsigned int h, float acc) {
#if __has_builtin(__builtin_amdgcn_fdot2)
  return __builtin_amdgcn_fdot2(__builtin_bit_cast(fp16x2, a),
                                __builtin_bit_cast(fp16x2, h), acc, false);
#else
  fp16x2 av = __builtin_bit_cast(fp16x2, a);
  fp16x2 hv = __builtin_bit_cast(fp16x2, h);
  return acc + (float)av[0] * (float)hv[0] + (float)av[1] * (float)hv[1];
#endif
}

// ---------------- weight prep (all 3 layers in one launch) ----------------
// Wt[n][k] bf16 from W[k][n] f32. W0: 256x256, W1/W2: 64x256.
__global__ __launch_bounds__(256) void wprep3_k(const float* __restrict__ W0,
                                                const float* __restrict__ W1,
                                                const float* __restrict__ W2,
                                                unsigned short* __restrict__ T0,
                                                unsigned short* __restrict__ T1,
                                                unsigned short* __restrict__ T2) {
  int i = blockIdx.x * 256 + threadIdx.x;
  if (i < 65536) {
    int k = i >> 8, n = i & 255;
    T0[n * 256 + k] = f2bf(W0[i]);
  } else if (i < 81920) {
    int j = i - 65536, k = j >> 8, n = j & 255;
    T1[n * 64 + k] = f2bf(W1[j]);
  } else if (i < 98304) {
    int j = i - 81920, k = j >> 8, n = j & 255;
    T2[n * 64 + k] = f2bf(W2[j]);
  }
}

// ---------------- fused MFMA GEMM + attention-dot epilogue ----------------
// h table written in f16, channel-major [node][chan][head].
// B fragments loaded directly from global Wt (L2-resident) - no Bs LDS tile.
__global__ __launch_bounds__(256) void mfma_gat_k(const float* __restrict__ Af,
                                                  const unsigned short* __restrict__ Ab,
                                                  const unsigned short* __restrict__ Wt,
                                                  const float* __restrict__ att_s,
                                                  const float* __restrict__ att_d,
                                                  unsigned short* __restrict__ ht16,
                                                  float* __restrict__ a_src,
                                                  float* __restrict__ a_dst,
                                                  int M, int K, int a_is_f32) {
  __shared__ unsigned short As[32 * 40];    // [row][k] stride 40 (pad)
  __shared__ unsigned short Cs[32 * 258];   // [row][chan*4+head] channel-major f16

  int tid = threadIdx.x;
  int bm = blockIdx.x * 32;
  int w = tid >> 6, l = tid & 63;
  int lr = l & 15, lk = l >> 4;
  int row_s = tid >> 3, seg = tid & 7;

  f32x4 acc[2][4];
  #pragma unroll
  for (int rt = 0; rt < 2; ++rt)
    #pragma unroll
    for (int ct = 0; ct < 4; ++ct) {
      f32x4 z = {0.f, 0.f, 0.f, 0.f};
      acc[rt][ct] = z;
    }

  const unsigned short* wp0 = Wt + (size_t)(w * 64 + lr) * K + lk * 8;

  for (int k0 = 0; k0 < K; k0 += 32) {
    if (a_is_f32) {
      float4 v = make_float4(0.f, 0.f, 0.f, 0.f);
      if (bm + row_s < M)
        v = *reinterpret_cast<const float4*>(Af + (size_t)(bm + row_s) * K + k0 + seg * 4);
      ushort4 u;
      u.x = f2bf(v.x); u.y = f2bf(v.y); u.z = f2bf(v.z); u.w = f2bf(v.w);
      *reinterpret_cast<ushort4*>(&As[row_s * 40 + seg * 4]) = u;
    } else {
      ushort4 u = make_ushort4(0, 0, 0, 0);
      if (bm + row_s < M)
        u = *reinterpret_cast<const ushort4*>(Ab + (size_t)(bm + row_s) * K + k0 + seg * 4);
      *reinterpret_cast<ushort4*>(&As[row_s * 40 + seg * 4]) = u;
    }
    // B fragments direct from global (L2-hot Wt)
    short8 bfr[4];
    #pragma unroll
    for (int ct = 0; ct < 4; ++ct)
      bfr[ct] = *reinterpret_cast<const short8*>(wp0 + (size_t)ct * 16 * K + k0);
    __syncthreads();
    #pragma unroll
    for (int rt = 0; rt < 2; ++rt) {
      short8 af = *reinterpret_cast<const short8*>(&As[(rt * 16 + lr) * 40 + lk * 8]);
      #pragma unroll
      for (int ct = 0; ct < 4; ++ct)
        acc[rt][ct] = __builtin_amdgcn_mfma_f32_16x16x32_bf16(af, bfr[ct], acc[rt][ct], 0, 0, 0);
    }
    __syncthreads();
  }

  #pragma unroll
  for (int rt = 0; rt < 2; ++rt)
    #pragma unroll
    for (int ct = 0; ct < 4; ++ct)
      #pragma unroll
      for (int r = 0; r < 4; ++r) {
        int row = rt * 16 + lk * 4 + r;
        int c = ct * 16 + lr;
        Cs[row * 258 + c * 4 + w] = f16b(acc[rt][ct][r]);
      }
  __syncthreads();

  if (bm + row_s < M) {
    ushort4* dst = reinterpret_cast<ushort4*>(ht16 + (size_t)(bm + row_s) * HC + seg * 32);
    const unsigned short* srcp = &Cs[row_s * 258 + seg * 32];
    #pragma unroll
    for (int q = 0; q < 4; ++q)
      dst[q] = *reinterpret_cast<const ushort4*>(srcp + q * 4);
  }

  {
    int nd = tid >> 3, q = tid & 7, h = q >> 1, half = q & 1;
    float ps = 0.f, pd = 0.f;
    const float* ats = att_s + h * 64 + half * 32;
    const float* atd = att_d + h * 64 + half * 32;
    const unsigned short* cp = &Cs[nd * 258 + (half * 32) * 4 + h];
    #pragma unroll
    for (int c = 0; c < 32; ++c) {
      float hv = (float)__builtin_bit_cast(f16_t, cp[c * 4]);
      ps += hv * ats[c];
      pd += hv * atd[c];
    }
    ps += __shfl_xor(ps, 1);
    pd += __shfl_xor(pd, 1);
    if (!(q & 1) && bm + nd < M) {
      a_src[(size_t)(bm + nd) * 4 + h] = ps;
      a_dst[(size_t)(bm + nd) * 4 + h] = pd;
    }
  }
}

// ================= CSR build (once per call) =================
__global__ __launch_bounds__(256) void hist_k(const int* __restrict__ dst, int* __restrict__ count, int E) {
  int e = blockIdx.x * blockDim.x + threadIdx.x;
  if (e < E) atomicAdd(&count[dst[e]], 1);
}

__global__ __launch_bounds__(512) void scan1_k(const int* __restrict__ count,
                                               int* __restrict__ rp,
                                               int* __restrict__ bsum, int n) {
  __shared__ int sh[512];
  int tx = threadIdx.x;
  int i = blockIdx.x * 512 + tx;
  int v = (i < n) ? count[i] : 0;
  sh[tx] = v;
  __syncthreads();
  #pragma unroll
  for (int off = 1; off < 512; off <<= 1) {
    int t = (tx >= off) ? sh[tx - off] : 0;
    __syncthreads();
    sh[tx] += t;
    __syncthreads();
  }
  if (i < n) rp[i] = sh[tx] - v;          // exclusive
  if (tx == 511) bsum[blockIdx.x] = sh[511];
}

__global__ __launch_bounds__(128) void scan2_k(int* __restrict__ bsum, int nb) {
  __shared__ int sh[128];
  int tx = threadIdx.x;
  int v = (tx < nb) ? bsum[tx] : 0;
  sh[tx] = v;
  __syncthreads();
  #pragma unroll
  for (int off = 1; off < 128; off <<= 1) {
    int t = (tx >= off) ? sh[tx - off] : 0;
    __syncthreads();
    sh[tx] += t;
    __syncthreads();
  }
  if (tx < nb) bsum[tx] = sh[tx] - v;      // exclusive
}

__global__ __launch_bounds__(512) void scan3_k(int* __restrict__ rp, const int* __restrict__ bsum,
                                               int n, int E) {
  int i = blockIdx.x * 512 + threadIdx.x;
  if (i < n) rp[i] += bsum[blockIdx.x];
  if (i == 0) rp[n] = E;
}

__global__ __launch_bounds__(256) void scatter_k(const int* __restrict__ src, const int* __restrict__ dst,
                                                 const int* __restrict__ rp, int* __restrict__ cursor,
                                                 int* __restrict__ csr_src, int E) {
  int e = blockIdx.x * blockDim.x + threadIdx.x;
  if (e >= E) return;
  int d = dst[e];
  int pos = rp[d] + atomicAdd(&cursor[d], 1);
  csr_src[pos] = src[e];
}

// ------------- FUSED segment softmax + gather-aggregate + finalize -------------
// One wave per node. Lane = (edge_slot, head) = (lane&15, lane>>4):
// 16-wide scalar reductions. Chunks 0+1 (32 edges) register-cached.
// Alphas packed f16 into per-edge 16B LDS records {a_h0..h3, s};
// aggregation reads records at wave-uniform addresses (broadcast), gather
// base scalarized via readfirstlane, 2x fdot2 per edge, 8-deep unroll.
__global__ __launch_bounds__(256) void soft_agg_k(const int* __restrict__ rp,
                                                  const int* __restrict__ csr_src,
                                                  const float* __restrict__ a_src,
                                                  const float* __restrict__ a_dst,
                                                  const unsigned short* __restrict__ ht16,
                                                  const float* __restrict__ bias,
                                                  float* __restrict__ outf,
                                                  unsigned short* __restrict__ outb,
                                                  int N, int do_lsm) {
  __shared__ uint4 rec[4][17];              // 16 edge records + self record per wave
  int tid  = threadIdx.x;
  int w    = tid >> 6;
  int lane = tid & 63;
  int wid  = (blockIdx.x * blockDim.x + tid) >> 6;
  if (wid >= N) return;
  int rs = rp[wid], re = rp[wid + 1];
  int ep = lane & 15;          // edge slot in chunk
  int h  = lane >> 4;          // head

  float adh = a_dst[(size_t)wid * 4 + h];
  float ash = a_src[(size_t)wid * 4 + h];
  float es  = lrelu(ash + adh);

  // ---- phase A: max over all edges (chunks 0,1 cached in regs) ----
  int s0 = 0, s1 = 0;
  float e0 = NEGBIG, e1 = NEGBIG;
  if (rs + ep < re) {
    s0 = csr_src[rs + ep];
    e0 = lrelu(a_src[(size_t)s0 * 4 + h] + adh);
  }
  if (rs + 16 + ep < re) {
    s1 = csr_src[rs + 16 + ep];
    e1 = lrelu(a_src[(size_t)s1 * 4 + h] + adh);
  }
  float m = fmaxf(es, fmaxf(e0, e1));
  for (int base = rs + 32; base < re; base += 16) {   // rare (deg > 32)
    if (base + ep < re) {
      int s = csr_src[base + ep];
      m = fmaxf(m, lrelu(a_src[(size_t)s * 4 + h] + adh));
    }
  }
  #pragma unroll
  for (int off = 8; off > 0; off >>= 1) m = fmaxf(m, __shfl_xor(m, off));

  // ---- phase B: denominator (p0,p1 stay in regs) ----
  float p0 = expf(e0 - m), p1 = expf(e1 - m);         // 0 for invalid slots
  float dn = p0 + p1;
  for (int base = rs + 32; base < re; base += 16) {   // rare
    if (base + ep < re) {
      int s = csr_src[base + ep];
      dn += expf(lrelu(a_src[(size_t)s * 4 + h] + adh) - m);
    }
  }
  #pragma unroll
  for (int off = 8; off > 0; off >>= 1) dn += __shfl_xor(dn, off);
  float sp = expf(es - m);
  dn += sp;
  float rr = 1.f / (dn + EPSV);

  // ---- phase C: alpha records in LDS + dot2 aggregation ----
  unsigned short* recb = reinterpret_cast<unsigned short*>(&rec[w][0]);
  float acc = 0.f;
  const unsigned short* hl = ht16 + lane * 4;   // lane = channel in agg phase

  auto agg = [&](int cnt) {
    int k = 0;
    for (; k + 8 <= cnt; k += 8) {
      uint4 r0 = rec[w][k + 0], r1 = rec[w][k + 1];
      uint4 r2 = rec[w][k + 2], r3 = rec[w][k + 3];
      uint4 r4 = rec[w][k + 4], r5 = rec[w][k + 5];
      uint4 r6 = rec[w][k + 6], r7 = rec[w][k + 7];
      int t0 = __builtin_amdgcn_readfirstlane((int)r0.z);
      int t1 = __builtin_amdgcn_readfirstlane((int)r1.z);
      int t2 = __builtin_amdgcn_readfirstlane((int)r2.z);
      int t3 = __builtin_amdgcn_readfirstlane((int)r3.z);
      int t4 = __builtin_amdgcn_readfirstlane((int)r4.z);
      int t5 = __builtin_amdgcn_readfirstlane((int)r5.z);
      int t6 = __builtin_amdgcn_readfirstlane((int)r6.z);
      int t7 = __builtin_amdgcn_readfirstlane((int)r7.z);
      uint2 h0 = *reinterpret_cast<const uint2*>(hl + (size_t)t0 * HC);
      uint2 h1 = *reinterpret_cast<const uint2*>(hl + (size_t)t1 * HC);
      uint2 h2 = *reinterpret_cast<const uint2*>(hl + (size_t)t2 * HC);
      uint2 h3 = *reinterpret_cast<const uint2*>(hl + (size_t)t3 * HC);
      uint2 h4 = *reinterpret_cast<const uint2*>(hl + (size_t)t4 * HC);
      uint2 h5 = *reinterpret_cast<const uint2*>(hl + (size_t)t5 * HC);
      uint2 h6 = *reinterpret_cast<const uint2*>(hl + (size_t)t6 * HC);
      uint2 h7 = *reinterpret_cast<const uint2*>(hl + (size_t)t7 * HC);
      acc = dot2acc(r0.x, h0.x, acc); acc = dot2acc(r0.y, h0.y, acc);
      acc = dot2acc(r1.x, h1.x, acc); acc = dot2acc(r1.y, h1.y, acc);
      acc = dot2acc(r2.x, h2.x, acc); acc = dot2acc(r2.y, h2.y, acc);
      acc = dot2acc(r3.x, h3.x, acc); acc = dot2acc(r3.y, h3.y, acc);
      acc = dot2acc(r4.x, h4.x, acc); acc = dot2acc(r4.y, h4.y, acc);
      acc = dot2acc(r5.x, h5.x, acc); acc = dot2acc(r5.y, h5.y, acc);
      acc = dot2acc(r6.x, h6.x, acc); acc = dot2acc(r6.y, h6.y, acc);
      acc = dot2acc(r7.x, h7.x, acc); acc = dot2acc(r7.y, h7.y, acc);
    }
    for (; k + 4 <= cnt; k += 4) {
      uint4 r0 = rec[w][k + 0], r1 = rec[w][k + 1];
      uint4 r2 = rec[w][k + 2], r3 = rec[w][k + 3];
      int t0 = __builtin_amdgcn_readfirstlane((int)r0.z);
      int t1 = __builtin_amdgcn_readfirstlane((int)r1.z);
      int t2 = __builtin_amdgcn_readfirstlane((int)r2.z);
      int t3 = __builtin_amdgcn_readfirstlane((int)r3.z);
      uint2 h0 = *reinterpret_cast<const uint2*>(hl + (size_t)t0 * HC);
      uint2 h1 = *reinterpret_cast<const uint2*>(hl + (size_t)t1 * HC);
      uint2 h2 = *reinterpret_cast<const uint2*>(hl + (size_t)t2 * HC);
      uint2 h3 = *reinterpret_cast<const uint2*>(hl + (size_t)t3 * HC);
      acc = dot2acc(r0.x, h0.x, acc); acc = dot2acc(r0.y, h0.y, acc);
      acc = dot2acc(r1.x, h1.x, acc); acc = dot2acc(r1.y, h1.y, acc);
      acc = dot2acc(r2.x, h2.x, acc); acc = dot2acc(r2.y, h2.y, acc);
      acc = dot2acc(r3.x, h3.x, acc); acc = dot2acc(r3.y, h3.y, acc);
    }
    for (; k < cnt; ++k) {
      uint4 r0 = rec[w][k];
      int t0 = __builtin_amdgcn_readfirstlane((int)r0.z);
      uint2 hv = *reinterpret_cast<const uint2*>(hl + (size_t)t0 * HC);
      acc = dot2acc(r0.x, hv.x, acc);
      acc = dot2acc(r0.y, hv.y, acc);
    }
  };

  // self record (slot 16) + chunk 0
  if (ep == 0) recb[16 * 8 + h] = f16b(sp * rr);
  recb[ep * 8 + h] = f16b(p0 * rr);
  if (h == 0) *reinterpret_cast<int*>(recb + ep * 8 + 4) = s0;
  {
    int cnt = re - rs; if (cnt > 16) cnt = 16;
    agg(cnt);
  }
  // chunk 1 (register-cached)
  if (re > rs + 16) {
    recb[ep * 8 + h] = f16b(p1 * rr);
    if (h == 0) *reinterpret_cast<int*>(recb + ep * 8 + 4) = s1;
    int cnt = re - rs - 16; if (cnt > 16) cnt = 16;
    agg(cnt);
  }
  // extra chunks (deg > 32, rare): recompute
  for (int base = rs + 32; base < re; base += 16) {
    int s = 0;
    float e = NEGBIG;
    if (base + ep < re) {
      s = csr_src[base + ep];
      e = lrelu(a_src[(size_t)s * 4 + h] + adh);
    }
    recb[ep * 8 + h] = f16b(expf(e - m) * rr);
    if (h == 0) *reinterpret_cast<int*>(recb + ep * 8 + 4) = s;
    int cnt = re - base; if (cnt > 16) cnt = 16;
    agg(cnt);
  }

  // ---- self message + finalize ----
  uint2 sa = *reinterpret_cast<const uint2*>(&rec[w][16]);   // uniform
  uint2 shv = *reinterpret_cast<const uint2*>(ht16 + (size_t)wid * HC + lane * 4);
  acc = dot2acc(sa.x, shv.x, acc);
  acc = dot2acc(sa.y, shv.y, acc);
  float v = acc * 0.25f + bias[lane];
  v = fmaxf(v, 0.f);
  if (do_lsm) {
    float mx = v;
    #pragma unroll
    for (int off = 32; off > 0; off >>= 1) mx = fmaxf(mx, __shfl_xor(mx, off));
    float ex = expf(v - mx);
    float sm = ex;
    #pragma unroll
    for (int off = 32; off > 0; off >>= 1) sm += __shfl_xor(sm, off);
    outf[(size_t)wid * CH + lane] = v - mx - logf(sm);
  } else {
    outb[(size_t)wid * CH + lane] = f2bf(v);
  }
}

extern "C" void kernel_launch(void* const* d_in, const int* in_sizes, int n_in,
                              void* d_out, int out_size, void* d_ws, size_t ws_size,
                              hipStream_t stream) {
  const float* x0 = (const float*)d_in[0];
  const int*   ei = (const int*)d_in[1];
  int N = in_sizes[0] / HC;   // 50000
  int E = in_sizes[1] / 2;    // 800000
  const int* srcp = ei;
  const int* dstp = ei + E;

  const float* W[3]  = {(const float*)d_in[2], (const float*)d_in[6],  (const float*)d_in[10]};
  const float* AS[3] = {(const float*)d_in[3], (const float*)d_in[7],  (const float*)d_in[11]};
  const float* AD[3] = {(const float*)d_in[4], (const float*)d_in[8],  (const float*)d_in[12]};
  const float* BI[3] = {(const float*)d_in[5], (const float*)d_in[9],  (const float*)d_in[13]};
  int Kdim[3] = {256, 64, 64};

  char* ws = (char*)d_ws;
  size_t off = 0;
  auto alloc = [&](size_t bytes) {
    void* p = ws + off;
    off += (bytes + 255) & ~(size_t)255;
    return p;
  };
  unsigned short* ht16    = (unsigned short*)alloc((size_t)N * HC * 2); // 25.6 MB (f16)
  unsigned short* xb16    = (unsigned short*)alloc((size_t)N * CH * 2); // 6.4 MB (bf16)
  float*          a_s     = (float*)alloc((size_t)N * 4 * 4);
  float*          a_d     = (float*)alloc((size_t)N * 4 * 4);
  int*            rowp    = (int*)alloc((size_t)(N + 1) * 4);
  int*            cursor  = (int*)alloc((size_t)N * 4);
  int*            csr_src = (int*)alloc((size_t)E * 4);                 // 3.2 MB
  int*            bsum    = (int*)alloc(512 * 4);
  unsigned short* Wt[3];
  Wt[0] = (unsigned short*)alloc((size_t)256 * 256 * 2);
  Wt[1] = (unsigned short*)alloc((size_t)256 * 64 * 2);
  Wt[2] = (unsigned short*)alloc((size_t)256 * 64 * 2);

  // ---- weight prep (bf16 transposed, all layers, one launch) ----
  wprep3_k<<<384, 256, 0, stream>>>(W[0], W[1], W[2], Wt[0], Wt[1], Wt[2]);

  // ---- build CSR by destination (once; reused by all 3 layers) ----
  int nb = (N + 511) / 512;
  hipMemsetAsync(cursor, 0, (size_t)N * 4, stream);
  hipMemsetAsync(rowp, 0, (size_t)N * 4, stream);
  hist_k<<<(E + 255) / 256, 256, 0, stream>>>(dstp, rowp, E);
  scan1_k<<<nb, 512, 0, stream>>>(rowp, rowp, bsum, N);
  scan2_k<<<1, 128, 0, stream>>>(bsum, nb);
  scan3_k<<<nb, 512, 0, stream>>>(rowp, bsum, N, E);
  scatter_k<<<(E + 255) / 256, 256, 0, stream>>>(srcp, dstp, rowp, cursor, csr_src, E);

  for (int L = 0; L < 3; ++L) {
    int K = Kdim[L];
    mfma_gat_k<<<(N + 31) / 32, 256, 0, stream>>>(
        (L == 0) ? x0 : nullptr, (L == 0) ? nullptr : xb16,
        Wt[L], AS[L], AD[L], ht16, a_s, a_d, N, K, (L == 0) ? 1 : 0);
    soft_agg_k<<<(N + 3) / 4, 256, 0, stream>>>(rowp, csr_src, a_s, a_d, ht16, BI[L],
                                                (float*)d_out, xb16, N, (L == 2) ? 1 : 0);
  }
}